// Round 8
// baseline (289.913 us; speedup 1.0000x reference)
//
#include <hip/hip_runtime.h>

// ---------------------------------------------------------------------------
// Linear attention (causal, phi = elu+1), B=2 T=2048 H=16 dk=64 D=1024.
// r17 FAILED: hipLaunchCooperativeKernel is not graph-capturable -> launch
// silently dropped, output stayed zero (absmax 3.0 = max|ref|).
// r18: same fused mega-kernel, but SOFTWARE grid barrier + plain launch:
//  - 768 blocks = 3/CU exactly (launch_bounds(256,3); LDS 36.9KB; VGPR<=168)
//    -> all blocks co-resident, barrier cannot starve.
//  - sense-reversing barrier, agent-scope atomics (coherent point) +
//    agent-scope release/acquire fences per block -> every XCD's L2 is
//    written back before arrival and invalidated after release (G16).
//  - barrier state = 128B of ws at +65MB, zeroed via capturable
//    hipMemsetAsync before the launch.
// World B evidence (r14 algebra): warm kernels sum ~66us, gaps ~95us
// (~16us/launch). 5 barriers (~2-4us each) replace 5 gaps.
// ---------------------------------------------------------------------------

typedef float  f32x4   __attribute__((ext_vector_type(4)));
typedef __bf16 bf16x8  __attribute__((ext_vector_type(8)));
typedef short  short8v __attribute__((ext_vector_type(8)));
typedef short  short4v __attribute__((ext_vector_type(4)));

static __device__ __forceinline__ short f2bf(float f) {
    unsigned u = __float_as_uint(f);
    u += 0x7FFFu + ((u >> 16) & 1u);          // RNE
    return (short)(u >> 16);
}
static __device__ __forceinline__ float bf2f(short s) {
    return __uint_as_float(((unsigned)(unsigned short)s) << 16);
}
static __device__ __forceinline__ float phi(float x) {   // elu(x)+1
    return x > 0.f ? x + 1.f : __expf(x);
}
static __device__ __forceinline__ void gl_lds16(const short* g, short* l) {
    __builtin_amdgcn_global_load_lds(
        (const __attribute__((address_space(1))) void*)g,
        (__attribute__((address_space(3))) void*)l, 16, 0, 0);
}

#define LDT 72   // 64x64 tile leading dim
static __device__ __forceinline__ int swz(int row, int col) {
    return row * LDT + (col ^ (row & 56));
}

#define NBLK 768

// Sense-reversing grid barrier. arrive @ bar[0], gen @ bar[32] (separate
// cachelines). Release fence (buffer_wbl2 on this XCD) before arrival;
// acquire fence (invalidate) after the generation bump is observed.
static __device__ __forceinline__ void gbar(unsigned* bar) {
    __syncthreads();                       // drains vmcnt/lgkmcnt per wave
    if (threadIdx.x == 0) {
        unsigned* arrive = bar;
        unsigned* gen    = bar + 32;
        __builtin_amdgcn_fence(__ATOMIC_RELEASE, "agent");
        unsigned g = __hip_atomic_load(gen, __ATOMIC_RELAXED, __HIP_MEMORY_SCOPE_AGENT);
        unsigned a = __hip_atomic_fetch_add(arrive, 1u, __ATOMIC_RELAXED, __HIP_MEMORY_SCOPE_AGENT);
        if (a == NBLK - 1u) {
            __hip_atomic_store(arrive, 0u, __ATOMIC_RELAXED, __HIP_MEMORY_SCOPE_AGENT);
            __hip_atomic_store(gen, g + 1u, __ATOMIC_RELEASE, __HIP_MEMORY_SCOPE_AGENT);
        } else {
            while (__hip_atomic_load(gen, __ATOMIC_RELAXED, __HIP_MEMORY_SCOPE_AGENT) == g)
                __builtin_amdgcn_s_sleep(8);
        }
        __builtin_amdgcn_fence(__ATOMIC_ACQUIRE, "agent");
    }
    __syncthreads();
}

__global__ __launch_bounds__(256, 3) void mega(
    const float* __restrict__ x,
    const float* __restrict__ Wq, const float* __restrict__ bq,
    const float* __restrict__ Wk, const float* __restrict__ bk,
    const float* __restrict__ Wv, const float* __restrict__ bv,
    const float* __restrict__ Wo, const float* __restrict__ bo,
    char* __restrict__ ws, float* __restrict__ outp)
{
    __shared__ __align__(16) char smem[36864];   // phase-reused arena

    const int bid = blockIdx.x;                  // 0..767
    const int tid = threadIdx.x;
    const int wave = tid >> 6, lane = tid & 63;
    const int l15 = lane & 15, quad = lane >> 4;

    short* xb     = (short*)(ws + 0);            //  8 MB [4096][1024] bf16
    short* Wqb    = (short*)(ws + 8388608);      //  2 MB
    short* Wkb    = (short*)(ws + 10485760);     //  2 MB
    short* Wvb    = (short*)(ws + 12582912);     //  2 MB
    short* Wob    = (short*)(ws + 14680064);     //  2 MB
    short* Qb     = (short*)(ws + 16777216);     //  8 MB [bh*2048+t][64]
    short* Kb     = (short*)(ws + 25165824);     //  8 MB
    short* Vb     = (short*)(ws + 33554432);     //  8 MB
    short* KVsum  = (short*)(ws + 41943040);     //  8 MB [bh][c][d*64+e]
    short* KVpref = (short*)(ws + 50331648);     //  8 MB
    short* attnb  = (short*)(ws + 58720256);     //  8 MB [b,t][h*64+e]
    float* ksum   = (float*)(ws + 67108864);     // 256 KB
    float* kpref  = (float*)(ws + 67371008);     // 256 KB
    unsigned* bar = (unsigned*)(ws + 68157440);  // barrier state (memset 0)

    // ======== Phase 0: fp32 -> bf16 conversion (4096 units, stride) ========
    for (int u = bid; u < 4096; u += NBLK) {
        const float* src; short* dst; size_t base;
        if (u < 2048)      { src = x;  dst = xb;  base = (size_t)u * 2048; }
        else if (u < 2560) { src = Wq; dst = Wqb; base = (size_t)(u - 2048) * 2048; }
        else if (u < 3072) { src = Wk; dst = Wkb; base = (size_t)(u - 2560) * 2048; }
        else if (u < 3584) { src = Wv; dst = Wvb; base = (size_t)(u - 3072) * 2048; }
        else               { src = Wo; dst = Wob; base = (size_t)(u - 3584) * 2048; }
        const size_t o = base + (size_t)tid * 8;
        f32x4 v0 = *(const f32x4*)&src[o];
        f32x4 v1 = *(const f32x4*)&src[o + 4];
        short8v s;
#pragma unroll
        for (int m = 0; m < 4; ++m) { s[m] = f2bf(v0[m]); s[m + 4] = f2bf(v1[m]); }
        *(short8v*)&dst[o] = s;
    }
    gbar(bar);

    // ======== Phase 1: fused QKV GEMM (128x128, BK=32, 2-phase) ============
    {
        short* Asb[2] = { (short*)smem,        (short*)smem + 4096 };
        short* Bsb[2] = { (short*)smem + 8192, (short*)smem + 12288 };
        const int bm = bid & 31, bn = bid >> 5;        // 32 x 24
        const int wsel = bn >> 3;                      // 0=Q 1=K 2=V
        const int n0 = (bn & 7) << 7;
        const short* __restrict__ W    = (wsel == 0) ? Wqb : (wsel == 1) ? Wkb : Wvb;
        const float* __restrict__ bias = (wsel == 0) ? bq  : (wsel == 1) ? bk  : bv;
        short* __restrict__ Ob         = (wsel == 0) ? Qb  : (wsel == 1) ? Kb  : Vb;
        const int m0 = bm << 7;
        const int wm = (wave & 1) << 6, wn = (wave >> 1) << 6;

        const int ch0 = wave * 2, ch1 = ch0 + 1;
        const int lrow = lane >> 2;
        const int lcol = (((lane & 3) ^ ((lane >> 3) & 3)) << 3);   // r15 swizzle
        const short* ga0 = xb + (size_t)(m0 + ch0 * 16 + lrow) * 1024 + lcol;
        const short* ga1 = xb + (size_t)(m0 + ch1 * 16 + lrow) * 1024 + lcol;
        const short* gb0 = W  + (size_t)(n0 + ch0 * 16 + lrow) * 1024 + lcol;
        const short* gb1 = W  + (size_t)(n0 + ch1 * 16 + lrow) * 1024 + lcol;
        short* la0[2] = { Asb[0] + ch0 * 512, Asb[1] + ch0 * 512 };
        short* la1[2] = { Asb[0] + ch1 * 512, Asb[1] + ch1 * 512 };
        short* lb0[2] = { Bsb[0] + ch0 * 512, Bsb[1] + ch0 * 512 };
        short* lb1[2] = { Bsb[0] + ch1 * 512, Bsb[1] + ch1 * 512 };
        const int rslot = (quad ^ ((l15 >> 1) & 3)) << 3;           // r15 swizzle

#define QKV_STAGE(K, BUF)                    \
    do {                                     \
        gl_lds16(ga0 + (K), la0[BUF]);       \
        gl_lds16(ga1 + (K), la1[BUF]);       \
        gl_lds16(gb0 + (K), lb0[BUF]);       \
        gl_lds16(gb1 + (K), lb1[BUF]);       \
    } while (0)
#define QKV_COMPUTE(BUF)                                                              \
    do {                                                                              \
        bf16x8 a[4], b[4];                                                            \
        _Pragma("unroll")                                                             \
        for (int i = 0; i < 4; ++i)                                                   \
            a[i] = *(const bf16x8*)&Asb[BUF][(wm + i * 16 + l15) * 32 + rslot];       \
        _Pragma("unroll")                                                             \
        for (int j = 0; j < 4; ++j)                                                   \
            b[j] = *(const bf16x8*)&Bsb[BUF][(wn + j * 16 + l15) * 32 + rslot];       \
        _Pragma("unroll")                                                             \
        for (int i = 0; i < 4; ++i)                                                   \
            _Pragma("unroll")                                                         \
            for (int j = 0; j < 4; ++j)                                               \
                acc[i][j] = __builtin_amdgcn_mfma_f32_16x16x32_bf16(a[i], b[j],       \
                                                                   acc[i][j], 0, 0, 0); \
    } while (0)

        f32x4 acc[4][4] = {};
        QKV_STAGE(0, 0);
        for (int k0 = 0; k0 < 1024; k0 += 64) {
            asm volatile("s_waitcnt vmcnt(0)" ::: "memory");
            __syncthreads();
            QKV_STAGE(k0 + 32, 1);
            QKV_COMPUTE(0);
            asm volatile("s_waitcnt vmcnt(0)" ::: "memory");
            __syncthreads();
            if (k0 + 64 < 1024) QKV_STAGE(k0 + 64, 0);
            QKV_COMPUTE(1);
        }
#undef QKV_STAGE
#undef QKV_COMPUTE

#pragma unroll
        for (int i = 0; i < 4; ++i)
#pragma unroll
            for (int j = 0; j < 4; ++j) {
                const int col = n0 + wn + j * 16 + l15;     // h*64 + d
                const int h = col >> 6, d = col & 63;
                const float bv_ = bias[col];
                const int row0 = m0 + wm + i * 16 + quad * 4;   // b*2048 + t0
                const int b = row0 >> 11, t0 = row0 & 2047;
                const size_t obase = ((size_t)(b * 16 + h) * 2048 + t0) * 64 + d;
#pragma unroll
                for (int r = 0; r < 4; ++r) {
                    float v = acc[i][j][r] + bv_;
                    if (wsel < 2) v = phi(v);
                    Ob[obase + (size_t)r * 64] = f2bf(v);
                }
            }
    }
    gbar(bar);

    // ======== Phase 2: per-chunk KV state (1024 tiles, stride) =============
    {
        short* KT = (short*)smem;            // [64][LDT] swizzled
        short* VT = KT + 4608;
        float* pS = (float*)(VT + 4608);     // 256 floats
        const int w = wave;
        for (int tidx = bid; tidx < 1024; tidx += NBLK) {
            const int c = tidx & 31, bh = tidx >> 5;
            const size_t tilebase = ((size_t)bh * 2048 + c * 64) * 64;
            __syncthreads();   // prior iteration LDS readers done
#pragma unroll
            for (int p = 0; p < 2; ++p) {
                const int t = (tid >> 3) + p * 32;
                const int e0 = (tid & 7) << 3;
                const size_t g = tilebase + (size_t)t * 64 + e0;
                short8v kv = *(const short8v*)&Kb[g];
                short8v vv = *(const short8v*)&Vb[g];
#pragma unroll
                for (int jj = 0; jj < 8; ++jj) {
                    KT[swz(e0 + jj, t)] = kv[jj];
                    VT[swz(e0 + jj, t)] = vv[jj];
                }
            }
            __syncthreads();

            f32x4 acc[4] = {};
#pragma unroll
            for (int k0 = 0; k0 < 64; k0 += 32) {
                const int ra = w * 16 + l15;
                bf16x8 a = *(const bf16x8*)&KT[ra * LDT + ((k0 + quad * 8) ^ (ra & 56))];
#pragma unroll
                for (int tj = 0; tj < 4; ++tj) {
                    const int rb = tj * 16 + l15;
                    bf16x8 bfr = *(const bf16x8*)&VT[rb * LDT + ((k0 + quad * 8) ^ (rb & 56))];
                    acc[tj] = __builtin_amdgcn_mfma_f32_16x16x32_bf16(a, bfr, acc[tj], 0, 0, 0);
                }
            }
            short* __restrict__ op = KVsum + (((size_t)bh * 32) + c) * 4096;   // [d][e]
#pragma unroll
            for (int tj = 0; tj < 4; ++tj)
#pragma unroll
                for (int r = 0; r < 4; ++r)
                    op[(w * 16 + quad * 4 + r) * 64 + tj * 16 + l15] = f2bf(acc[tj][r]);

            {   // ksum partials: thread = (part, d)
                const int d = tid & 63, part = tid >> 6;
                short8v k1 = *(const short8v*)&KT[d * LDT + ((part * 16) ^ (d & 56))];
                short8v k2 = *(const short8v*)&KT[d * LDT + ((part * 16 + 8) ^ (d & 56))];
                float s = 0.f;
#pragma unroll
                for (int m = 0; m < 8; ++m) s += bf2f(k1[m]) + bf2f(k2[m]);
                pS[part * 64 + d] = s;
            }
            __syncthreads();
            if (tid < 64)
                ksum[(((size_t)bh * 32) + c) * 64 + tid] =
                    pS[tid] + pS[tid + 64] + pS[tid + 128] + pS[tid + 192];
        }
    }
    gbar(bar);

    // ======== Phase 3: exclusive prefix scan (512 units) ===================
    if (bid < 512) {
        const int bx = bid & 15, bh = bid >> 4;
        const int o = bx * 256 + tid;
        const size_t base = (size_t)bh * 32 * 4096 + o;
        short v[32];
#pragma unroll
        for (int cc = 0; cc < 32; ++cc) v[cc] = KVsum[base + (size_t)cc * 4096];
        float run = 0.f;
#pragma unroll
        for (int cc = 0; cc < 32; ++cc) {
            KVpref[base + (size_t)cc * 4096] = f2bf(run);   // exclusive
            run += bf2f(v[cc]);
        }
        if (bx == 0 && tid < 64) {
            float vals[32];
            const size_t kb = (size_t)bh * 32 * 64 + tid;
#pragma unroll
            for (int cc = 0; cc < 32; ++cc) vals[cc] = ksum[kb + (size_t)cc * 64];
            float r2 = 0.f;
#pragma unroll
            for (int cc = 0; cc < 32; ++cc) { kpref[kb + (size_t)cc * 64] = r2; r2 += vals[cc]; }
        }
    }
    gbar(bar);

    // ======== Phase 4: per-chunk attention (1024 tiles, stride) ============
    {
        short* Qs  = (short*)smem;           // [64][LDT] straight
        short* KS  = Qs + 4608;              // K then masked S
        short* VTa = KS + 4608;              // V^T swizzled
        short* KVT = VTa + 4608;             // KVpref^T swizzled
        const int w = wave;
        for (int tidx = bid; tidx < 1024; tidx += NBLK) {
            const int c = tidx & 31, bh = tidx >> 5;
            const int b = bh >> 4, h = bh & 15;
            const size_t tilebase = ((size_t)bh * 2048 + c * 64) * 64;
            const short* __restrict__ KVc = KVpref + (((size_t)bh * 32) + c) * 4096;

            __syncthreads();   // prior iteration LDS readers done
#pragma unroll
            for (int p = 0; p < 2; ++p) {
                const int t = (tid >> 3) + p * 32;
                const int e0 = (tid & 7) << 3;
                const size_t g = tilebase + (size_t)t * 64 + e0;
                *(short8v*)&Qs[t * LDT + e0] = *(const short8v*)&Qb[g];
                *(short8v*)&KS[t * LDT + e0] = *(const short8v*)&Kb[g];
                short8v vv = *(const short8v*)&Vb[g];
                short8v pv = *(const short8v*)&KVc[t * 64 + e0];
#pragma unroll
                for (int jj = 0; jj < 8; ++jj) {
                    VTa[swz(e0 + jj, t)] = vv[jj];
                    KVT[swz(e0 + jj, t)] = pv[jj];
                }
            }
            __syncthreads();

            // S = Q K^T
            f32x4 sacc[4] = {};
#pragma unroll
            for (int k0 = 0; k0 < 64; k0 += 32) {
                bf16x8 a = *(const bf16x8*)&Qs[(w * 16 + l15) * LDT + k0 + quad * 8];
#pragma unroll
                for (int tj = 0; tj < 4; ++tj) {
                    bf16x8 bfr = *(const bf16x8*)&KS[(tj * 16 + l15) * LDT + k0 + quad * 8];
                    sacc[tj] = __builtin_amdgcn_mfma_f32_16x16x32_bf16(a, bfr, sacc[tj], 0, 0, 0);
                }
            }

            // z via masked rowsum + q.kpref, 16-lane butterfly
            f32x4 kp4 = *(const f32x4*)&kpref[(((size_t)bh * 32) + c) * 64 + l15 * 4];
            float zinv[4];
#pragma unroll
            for (int r = 0; r < 4; ++r) {
                const int i = w * 16 + quad * 4 + r;
                float p = 0.f;
#pragma unroll
                for (int tj = 0; tj < 4; ++tj)
                    if (tj * 16 + l15 <= i) p += sacc[tj][r];
                short4v q4 = *(const short4v*)&Qs[i * LDT + l15 * 4];
#pragma unroll
                for (int m = 0; m < 4; ++m) p += bf2f(q4[m]) * kp4[m];
                p += __shfl_xor(p, 1);
                p += __shfl_xor(p, 2);
                p += __shfl_xor(p, 4);
                p += __shfl_xor(p, 8);
                zinv[r] = 1.f / (p + 1e-6f);
            }

            __syncthreads();   // all waves done reading KS-as-K before overwrite
#pragma unroll
            for (int tj = 0; tj < 4; ++tj)
#pragma unroll
                for (int r = 0; r < 4; ++r) {
                    const int i = w * 16 + quad * 4 + r;
                    const int j = tj * 16 + l15;
                    KS[i * LDT + j] = f2bf(j <= i ? sacc[tj][r] : 0.f);
                }
            // NO barrier: O-MFMA a1 reads KS rows [w*16, w*16+16) - wave-private.

            // O = causal(S) V + Q KVpref
            f32x4 oacc[4] = {};
#pragma unroll
            for (int k0 = 0; k0 < 64; k0 += 32) {
                bf16x8 a1 = *(const bf16x8*)&KS[(w * 16 + l15) * LDT + k0 + quad * 8];
                bf16x8 a2 = *(const bf16x8*)&Qs[(w * 16 + l15) * LDT + k0 + quad * 8];
#pragma unroll
                for (int tj = 0; tj < 4; ++tj) {
                    const int rb = tj * 16 + l15;
                    bf16x8 b1 = *(const bf16x8*)&VTa[rb * LDT + ((k0 + quad * 8) ^ (rb & 56))];
                    bf16x8 b2 = *(const bf16x8*)&KVT[rb * LDT + ((k0 + quad * 8) ^ (rb & 56))];
                    oacc[tj] = __builtin_amdgcn_mfma_f32_16x16x32_bf16(a1, b1, oacc[tj], 0, 0, 0);
                    oacc[tj] = __builtin_amdgcn_mfma_f32_16x16x32_bf16(a2, b2, oacc[tj], 0, 0, 0);
                }
            }
            const size_t arowbase = (size_t)b * 2048 + c * 64;
#pragma unroll
            for (int tj = 0; tj < 4; ++tj)
#pragma unroll
                for (int r = 0; r < 4; ++r) {
                    const int i = w * 16 + quad * 4 + r;
                    const int e = tj * 16 + l15;
                    attnb[(arowbase + i) * 1024 + h * 64 + e] = f2bf(oacc[tj][r] * zinv[r]);
                }
        }
    }
    gbar(bar);

    // ======== Phase 5: output projection GEMM (512 units, 128x64) ==========
    if (bid < 512) {
        short* Aob[2] = { (short*)smem,        (short*)smem + 4096 };
        short* Bob[2] = { (short*)smem + 8192, (short*)smem + 10240 };
        const int bm = bid & 31, bn = bid >> 5;      // 32 x 16
        const int m0 = bm << 7, n0 = bn << 6;
        const int wm = (wave & 1) << 6, wn = (wave >> 1) << 5;

        const int lrow = lane >> 2;
        const int lcol = (((lane & 3) ^ ((lane >> 3) & 3)) << 3);   // r15 swizzle
        const short* gp[3]; short* lp[2][3];
#pragma unroll
        for (int cc = 0; cc < 3; ++cc) {
            const int ch = wave * 3 + cc;
            if (ch < 8) {
                gp[cc] = attnb + (size_t)(m0 + ch * 16 + lrow) * 1024 + lcol;
                lp[0][cc] = Aob[0] + ch * 512;
                lp[1][cc] = Aob[1] + ch * 512;
            } else {
                gp[cc] = Wob + (size_t)(n0 + (ch - 8) * 16 + lrow) * 1024 + lcol;
                lp[0][cc] = Bob[0] + (ch - 8) * 512;
                lp[1][cc] = Bob[1] + (ch - 8) * 512;
            }
        }
        const int rslot = (quad ^ ((l15 >> 1) & 3)) << 3;           // r15 swizzle

#define OUT_STAGE(K, BUF)                     \
    do {                                      \
        gl_lds16(gp[0] + (K), lp[BUF][0]);    \
        gl_lds16(gp[1] + (K), lp[BUF][1]);    \
        gl_lds16(gp[2] + (K), lp[BUF][2]);    \
    } while (0)
#define OUT_COMPUTE(BUF)                                                              \
    do {                                                                              \
        bf16x8 a[4], b[2];                                                            \
        _Pragma("unroll")                                                             \
        for (int i = 0; i < 4; ++i)                                                   \
            a[i] = *(const bf16x8*)&Aob[BUF][(wm + i * 16 + l15) * 32 + rslot];       \
        _Pragma("unroll")                                                             \
        for (int j = 0; j < 2; ++j)                                                   \
            b[j] = *(const bf16x8*)&Bob[BUF][(wn + j * 16 + l15) * 32 + rslot];       \
        _Pragma("unroll")                                                             \
        for (int i = 0; i < 4; ++i)                                                   \
            _Pragma("unroll")                                                         \
            for (int j = 0; j < 2; ++j)                                               \
                acc[i][j] = __builtin_amdgcn_mfma_f32_16x16x32_bf16(a[i], b[j],       \
                                                                   acc[i][j], 0, 0, 0); \
    } while (0)

        f32x4 acc[4][2] = {};
        OUT_STAGE(0, 0);
        for (int k0 = 0; k0 < 1024; k0 += 64) {
            asm volatile("s_waitcnt vmcnt(0)" ::: "memory");
            __syncthreads();
            OUT_STAGE(k0 + 32, 1);
            OUT_COMPUTE(0);
            asm volatile("s_waitcnt vmcnt(0)" ::: "memory");
            __syncthreads();
            if (k0 + 64 < 1024) OUT_STAGE(k0 + 64, 0);
            OUT_COMPUTE(1);
        }
#undef OUT_STAGE
#undef OUT_COMPUTE

#pragma unroll
        for (int i = 0; i < 4; ++i)
#pragma unroll
            for (int j = 0; j < 2; ++j) {
                const int col = n0 + wn + j * 16 + l15;
                const float bv_ = bo[col];
#pragma unroll
                for (int r = 0; r < 4; ++r) {
                    const int row = m0 + wm + i * 16 + quad * 4 + r;
                    outp[(size_t)row * 1024 + col] = acc[i][j][r] + bv_;
                }
            }
    }
}

// ---------------------------------------------------------------------------
extern "C" void kernel_launch(void* const* d_in, const int* in_sizes, int n_in,
                              void* d_out, int out_size, void* d_ws, size_t ws_size,
                              hipStream_t stream)
{
    const float* x  = (const float*)d_in[0];
    const float* Wq = (const float*)d_in[1];
    const float* bq = (const float*)d_in[2];
    const float* Wk = (const float*)d_in[3];
    const float* bk = (const float*)d_in[4];
    const float* Wv = (const float*)d_in[5];
    const float* bv = (const float*)d_in[6];
    const float* Wo = (const float*)d_in[7];
    const float* bo = (const float*)d_in[8];
    char* ws = (char*)d_ws;
    float* outp = (float*)d_out;

    // zero the grid-barrier state (capturable; stream-ordered before mega)
    hipMemsetAsync(ws + 68157440, 0, 256, stream);

    mega<<<dim3(NBLK), dim3(256), 0, stream>>>(
        x, Wq, bq, Wk, bk, Wv, bv, Wo, bo, ws, outp);
}

// Round 9
// 179.199 us; speedup vs baseline: 1.6178x; 1.6178x over previous
//
#include <hip/hip_runtime.h>

// ---------------------------------------------------------------------------
// Linear attention (causal, phi = elu+1), B=2 T=2048 H=16 dk=64 D=1024.
// r18 (fused mega, 290us): software grid barrier = L2 wb/inv per block per
// phase -> dead end. BUT it measured the harness fixed floor: ~60us
// (poison fill + memset + graph) on top of ~85-100us kernels. Gaps small.
// r19: multi-kernel again; both GEMMs get a 3-buffer pipeline with COUNTED
// vmcnt + raw s_barrier (T4): stage tile t+2 after step-t barrier, wait
// vmcnt(4) (qkv) / vmcnt(3) (out) so each tile's loads have ~2 compute
// phases of cover; no compiler vmcnt(0) drain. sched_barrier(0) after each
// s_barrier pins ds_reads (rule 18); buffers indexed compile-time via
// 3x-unroll (rule 20). LDS 48KB/36KB -> 3 blocks/CU kept.
// ---------------------------------------------------------------------------

typedef float  f32x4   __attribute__((ext_vector_type(4)));
typedef __bf16 bf16x8  __attribute__((ext_vector_type(8)));
typedef short  short8v __attribute__((ext_vector_type(8)));
typedef short  short4v __attribute__((ext_vector_type(4)));

static __device__ __forceinline__ short f2bf(float f) {
    unsigned u = __float_as_uint(f);
    u += 0x7FFFu + ((u >> 16) & 1u);          // RNE
    return (short)(u >> 16);
}
static __device__ __forceinline__ float bf2f(short s) {
    return __uint_as_float(((unsigned)(unsigned short)s) << 16);
}
static __device__ __forceinline__ float phi(float x) {   // elu(x)+1
    return x > 0.f ? x + 1.f : __expf(x);
}
static __device__ __forceinline__ void gl_lds16(const short* g, short* l) {
    __builtin_amdgcn_global_load_lds(
        (const __attribute__((address_space(1))) void*)g,
        (__attribute__((address_space(3))) void*)l, 16, 0, 0);
}

#define LDT 72   // 64x64 tile leading dim
static __device__ __forceinline__ int swz(int row, int col) {
    return row * LDT + (col ^ (row & 56));
}

// ---------------- Kernel 0: fp32 -> bf16 conversion ------------------------
__global__ __launch_bounds__(256) void convert_bf16(
    const float* __restrict__ x,  const float* __restrict__ Wq,
    const float* __restrict__ Wk, const float* __restrict__ Wv,
    const float* __restrict__ Wo,
    short* __restrict__ xb,  short* __restrict__ Wqb,
    short* __restrict__ Wkb, short* __restrict__ Wvb, short* __restrict__ Wob)
{
    const int blk = blockIdx.x;
    const float* src; short* dst; size_t base;
    if (blk < 2048)      { src = x;  dst = xb;  base = (size_t)blk * 2048; }
    else if (blk < 2560) { src = Wq; dst = Wqb; base = (size_t)(blk - 2048) * 2048; }
    else if (blk < 3072) { src = Wk; dst = Wkb; base = (size_t)(blk - 2560) * 2048; }
    else if (blk < 3584) { src = Wv; dst = Wvb; base = (size_t)(blk - 3072) * 2048; }
    else                 { src = Wo; dst = Wob; base = (size_t)(blk - 3584) * 2048; }
    const size_t o = base + (size_t)threadIdx.x * 8;
    f32x4 v0 = *(const f32x4*)&src[o];
    f32x4 v1 = *(const f32x4*)&src[o + 4];
    short8v s;
#pragma unroll
    for (int m = 0; m < 4; ++m) { s[m] = f2bf(v0[m]); s[m + 4] = f2bf(v1[m]); }
    *(short8v*)&dst[o] = s;
}

// ---------------- Kernel 1: fused QKV GEMM (128x128, BK=32, 3-buf) ---------
// Output layout: [(b*16+h)*2048 + t][64] bf16 for Q, K, V.
__global__ __launch_bounds__(256) void gemm_qkv(
    const short* __restrict__ xb,
    const short* __restrict__ Wqb, const short* __restrict__ Wkb,
    const short* __restrict__ Wvb,
    const float* __restrict__ bq, const float* __restrict__ bk,
    const float* __restrict__ bv,
    short* __restrict__ Qb, short* __restrict__ Kb, short* __restrict__ Vb)
{
    __shared__ short As[3][128 * 32];
    __shared__ short Bs[3][128 * 32];
    const int tid = threadIdx.x;
    const int bm = blockIdx.x, bn = blockIdx.y;      // 32 x 24
    const int wsel = bn >> 3;                        // 0=Q 1=K 2=V
    const int n0 = (bn & 7) << 7;
    const short* __restrict__ W    = (wsel == 0) ? Wqb : (wsel == 1) ? Wkb : Wvb;
    const float* __restrict__ bias = (wsel == 0) ? bq  : (wsel == 1) ? bk  : bv;
    short* __restrict__ Ob         = (wsel == 0) ? Qb  : (wsel == 1) ? Kb  : Vb;
    const int m0 = bm << 7;
    const int wave = tid >> 6, lane = tid & 63;
    const int wm = (wave & 1) << 6, wn = (wave >> 1) << 6;
    const int l15 = lane & 15, quad = lane >> 4;

    const int ch0 = wave * 2, ch1 = ch0 + 1;
    const int lrow = lane >> 2;
    // r15 swizzle: slot (lane&3) receives k-slot (lane&3)^((lane>>3)&3)
    const int lcol = (((lane & 3) ^ ((lane >> 3) & 3)) << 3);
    const short* ga0 = xb + (size_t)(m0 + ch0 * 16 + lrow) * 1024 + lcol;
    const short* ga1 = xb + (size_t)(m0 + ch1 * 16 + lrow) * 1024 + lcol;
    const short* gb0 = W  + (size_t)(n0 + ch0 * 16 + lrow) * 1024 + lcol;
    const short* gb1 = W  + (size_t)(n0 + ch1 * 16 + lrow) * 1024 + lcol;
    const int lo0 = ch0 * 512, lo1 = ch1 * 512;
    // read-side slot for fragment row: (l15>>1)&3
    const int rslot = (quad ^ ((l15 >> 1) & 3)) << 3;

#define QKV_STAGE(K, BUF)                        \
    do {                                         \
        gl_lds16(ga0 + (K), &As[BUF][lo0]);      \
        gl_lds16(ga1 + (K), &As[BUF][lo1]);      \
        gl_lds16(gb0 + (K), &Bs[BUF][lo0]);      \
        gl_lds16(gb1 + (K), &Bs[BUF][lo1]);      \
    } while (0)

#define QKV_COMPUTE(BUF)                                                              \
    do {                                                                              \
        bf16x8 a[4], b[4];                                                            \
        _Pragma("unroll")                                                             \
        for (int i = 0; i < 4; ++i)                                                   \
            a[i] = *(const bf16x8*)&As[BUF][(wm + i * 16 + l15) * 32 + rslot];        \
        _Pragma("unroll")                                                             \
        for (int j = 0; j < 4; ++j)                                                   \
            b[j] = *(const bf16x8*)&Bs[BUF][(wn + j * 16 + l15) * 32 + rslot];        \
        _Pragma("unroll")                                                             \
        for (int i = 0; i < 4; ++i)                                                   \
            _Pragma("unroll")                                                         \
            for (int j = 0; j < 4; ++j)                                               \
                acc[i][j] = __builtin_amdgcn_mfma_f32_16x16x32_bf16(a[i], b[j],       \
                                                                   acc[i][j], 0, 0, 0); \
    } while (0)

// One K-step: wait own stage(T) drained (vmcnt(4) leaves only stage(T+1)
// in flight), barrier -> all waves' tile-T data resident; stage T+2 into
// the buffer compute(T-1) just vacated; compute tile T.
#define QKV_STEP(T, RB, SB)                                   \
    do {                                                      \
        asm volatile("s_waitcnt vmcnt(4)" ::: "memory");      \
        __builtin_amdgcn_s_barrier();                         \
        __builtin_amdgcn_sched_barrier(0);                    \
        QKV_STAGE(((T) + 2) * 32, SB);                        \
        QKV_COMPUTE(RB);                                      \
    } while (0)

    f32x4 acc[4][4] = {};
    QKV_STAGE(0, 0);
    QKV_STAGE(32, 1);
    for (int u = 0; u < 10; ++u) {           // steps t = 3u .. 3u+2  (0..29)
        const int t = u * 3;
        QKV_STEP(t + 0, 0, 2);
        QKV_STEP(t + 1, 1, 0);
        QKV_STEP(t + 2, 2, 1);
    }
    // t = 30: stage(31) is the only possible in-flight stage
    asm volatile("s_waitcnt vmcnt(4)" ::: "memory");
    __builtin_amdgcn_s_barrier();
    __builtin_amdgcn_sched_barrier(0);
    QKV_COMPUTE(0);
    // t = 31: drain everything
    asm volatile("s_waitcnt vmcnt(0)" ::: "memory");
    __builtin_amdgcn_s_barrier();
    __builtin_amdgcn_sched_barrier(0);
    QKV_COMPUTE(1);
#undef QKV_STEP
#undef QKV_STAGE
#undef QKV_COMPUTE

#pragma unroll
    for (int i = 0; i < 4; ++i)
#pragma unroll
        for (int j = 0; j < 4; ++j) {
            const int col = n0 + wn + j * 16 + l15;     // h*64 + d
            const int h = col >> 6, d = col & 63;
            const float bv_ = bias[col];
            const int row0 = m0 + wm + i * 16 + quad * 4;   // b*2048 + t0
            const int b = row0 >> 11, t0 = row0 & 2047;
            const size_t obase = ((size_t)(b * 16 + h) * 2048 + t0) * 64 + d;
#pragma unroll
            for (int r = 0; r < 4; ++r) {
                float v = acc[i][j][r] + bv_;
                if (wsel < 2) v = phi(v);
                Ob[obase + (size_t)r * 64] = f2bf(v);
            }
        }
}

// ---------------- Kernel 2: per-chunk KV state: KV_c = K_c^T V_c, ksum_c ---
__global__ __launch_bounds__(256) void chunk_sums(
    const short* __restrict__ Kb, const short* __restrict__ Vb,
    short* __restrict__ KVsum, float* __restrict__ ksum)
{
    __shared__ short KT[64 * LDT];   // K^T : [d][t]  (swizzled cols)
    __shared__ short VT[64 * LDT];   // V^T : [e][t]  (swizzled cols)
    __shared__ float pS[256];
    const int c = blockIdx.x, bh = blockIdx.y;
    const int tid = threadIdx.x;
    const int w = tid >> 6, lane = tid & 63, l15 = lane & 15, quad = lane >> 4;
    const size_t tilebase = ((size_t)bh * 2048 + c * 64) * 64;

#pragma unroll
    for (int p = 0; p < 2; ++p) {
        const int t = (tid >> 3) + p * 32;
        const int e0 = (tid & 7) << 3;
        const size_t g = tilebase + (size_t)t * 64 + e0;   // contiguous 4KB span
        short8v kv = *(const short8v*)&Kb[g];
        short8v vv = *(const short8v*)&Vb[g];
#pragma unroll
        for (int jj = 0; jj < 8; ++jj) {
            KT[swz(e0 + jj, t)] = kv[jj];
            VT[swz(e0 + jj, t)] = vv[jj];
        }
    }
    __syncthreads();

    f32x4 acc[4] = {};
#pragma unroll
    for (int k0 = 0; k0 < 64; k0 += 32) {
        const int ra = w * 16 + l15;
        bf16x8 a = *(const bf16x8*)&KT[ra * LDT + ((k0 + quad * 8) ^ (ra & 56))];
#pragma unroll
        for (int tj = 0; tj < 4; ++tj) {
            const int rb = tj * 16 + l15;
            bf16x8 bfr = *(const bf16x8*)&VT[rb * LDT + ((k0 + quad * 8) ^ (rb & 56))];
            acc[tj] = __builtin_amdgcn_mfma_f32_16x16x32_bf16(a, bfr, acc[tj], 0, 0, 0);
        }
    }
    short* __restrict__ outp = KVsum + (((size_t)bh * 32) + c) * 4096;   // [d][e]
#pragma unroll
    for (int tj = 0; tj < 4; ++tj)
#pragma unroll
        for (int r = 0; r < 4; ++r)
            outp[(w * 16 + quad * 4 + r) * 64 + tj * 16 + l15] = f2bf(acc[tj][r]);

    {   // ksum partials: thread = (part, d)
        const int d = tid & 63, part = tid >> 6;
        short8v k1 = *(const short8v*)&KT[d * LDT + ((part * 16) ^ (d & 56))];
        short8v k2 = *(const short8v*)&KT[d * LDT + ((part * 16 + 8) ^ (d & 56))];
        float s = 0.f;
#pragma unroll
        for (int m = 0; m < 8; ++m) s += bf2f(k1[m]) + bf2f(k2[m]);
        pS[part * 64 + d] = s;
    }
    __syncthreads();
    if (tid < 64)
        ksum[(((size_t)bh * 32) + c) * 64 + tid] =
            pS[tid] + pS[tid + 64] + pS[tid + 128] + pS[tid + 192];
}

// ---------------- Kernel 3: exclusive prefix scan over 32 chunks -----------
__global__ __launch_bounds__(256) void scan_chunks(
    const short* __restrict__ KVsum, const float* __restrict__ ksum,
    short* __restrict__ KVpref, float* __restrict__ kpref)
{
    const int bh = blockIdx.y;
    const int o = blockIdx.x * 256 + threadIdx.x;     // 16 x 256 = 4096
    const size_t base = (size_t)bh * 32 * 4096 + o;
    short v[32];
#pragma unroll
    for (int cc = 0; cc < 32; ++cc) v[cc] = KVsum[base + (size_t)cc * 4096];
    float run = 0.f;
#pragma unroll
    for (int cc = 0; cc < 32; ++cc) {
        KVpref[base + (size_t)cc * 4096] = f2bf(run);   // exclusive
        run += bf2f(v[cc]);
    }
    if (blockIdx.x == 0 && threadIdx.x < 64) {
        float vals[32];
        const size_t kb = (size_t)bh * 32 * 64 + threadIdx.x;
#pragma unroll
        for (int cc = 0; cc < 32; ++cc) vals[cc] = ksum[kb + (size_t)cc * 64];
        float r2 = 0.f;
#pragma unroll
        for (int cc = 0; cc < 32; ++cc) { kpref[kb + (size_t)cc * 64] = r2; r2 += vals[cc]; }
    }
}

// ---------------- Kernel 4: per-chunk attention ----------------------------
__global__ __launch_bounds__(256) void attn_chunk(
    const short* __restrict__ Qb, const short* __restrict__ Kb,
    const short* __restrict__ Vb, const short* __restrict__ KVpref,
    const float* __restrict__ kpref, short* __restrict__ attnb)
{
    __shared__ short Qs[64 * LDT];
    __shared__ short KS[64 * LDT];   // K, then overwritten with masked S (straight)
    __shared__ short VT[64 * LDT];   // V^T  [e][t]  (swizzled)
    __shared__ short KVT[64 * LDT];  // KVpref^T [e][d]  (swizzled)
    const int c = blockIdx.x, bh = blockIdx.y;
    const int b = bh >> 4, h = bh & 15;
    const int tid = threadIdx.x;
    const int w = tid >> 6, lane = tid & 63, l15 = lane & 15, quad = lane >> 4;
    const size_t tilebase = ((size_t)bh * 2048 + c * 64) * 64;
    const short* __restrict__ KVc = KVpref + (((size_t)bh * 32) + c) * 4096;

#pragma unroll
    for (int p = 0; p < 2; ++p) {
        const int t = (tid >> 3) + p * 32;             // t for Q/K/V; d for KVpref
        const int e0 = (tid & 7) << 3;
        const size_t g = tilebase + (size_t)t * 64 + e0;  // contiguous 4KB span
        *(short8v*)&Qs[t * LDT + e0] = *(const short8v*)&Qb[g];
        *(short8v*)&KS[t * LDT + e0] = *(const short8v*)&Kb[g];
        short8v vv = *(const short8v*)&Vb[g];
        short8v pv = *(const short8v*)&KVc[t * 64 + e0];
#pragma unroll
        for (int jj = 0; jj < 8; ++jj) {
            VT[swz(e0 + jj, t)]  = vv[jj];
            KVT[swz(e0 + jj, t)] = pv[jj];
        }
    }
    __syncthreads();

    // ---- S = Q K^T ---------------------------------------------------------
    f32x4 sacc[4] = {};
#pragma unroll
    for (int k0 = 0; k0 < 64; k0 += 32) {
        bf16x8 a = *(const bf16x8*)&Qs[(w * 16 + l15) * LDT + k0 + quad * 8];
#pragma unroll
        for (int tj = 0; tj < 4; ++tj) {
            bf16x8 bfr = *(const bf16x8*)&KS[(tj * 16 + l15) * LDT + k0 + quad * 8];
            sacc[tj] = __builtin_amdgcn_mfma_f32_16x16x32_bf16(a, bfr, sacc[tj], 0, 0, 0);
        }
    }

    // ---- z via masked rowsum + q.kpref, 16-lane butterfly ------------------
    f32x4 kp4 = *(const f32x4*)&kpref[(((size_t)bh * 32) + c) * 64 + l15 * 4];
    float zinv[4];
#pragma unroll
    for (int r = 0; r < 4; ++r) {
        const int i = w * 16 + quad * 4 + r;
        float p = 0.f;
#pragma unroll
        for (int tj = 0; tj < 4; ++tj)
            if (tj * 16 + l15 <= i) p += sacc[tj][r];
        short4v q4 = *(const short4v*)&Qs[i * LDT + l15 * 4];
#pragma unroll
        for (int m = 0; m < 4; ++m) p += bf2f(q4[m]) * kp4[m];
        p += __shfl_xor(p, 1);
        p += __shfl_xor(p, 2);
        p += __shfl_xor(p, 4);
        p += __shfl_xor(p, 8);
        zinv[r] = 1.f / (p + 1e-6f);
    }

    __syncthreads();   // all waves done reading KS-as-K before overwrite
#pragma unroll
    for (int tj = 0; tj < 4; ++tj)
#pragma unroll
        for (int r = 0; r < 4; ++r) {
            const int i = w * 16 + quad * 4 + r;
            const int j = tj * 16 + l15;
            KS[i * LDT + j] = f2bf(j <= i ? sacc[tj][r] : 0.f);
        }
    // NO barrier: O-MFMA a1 reads KS rows [w*16, w*16+16) - wave-private.

    // ---- O = causal(S) V + Q KVpref ---------------------------------------
    f32x4 oacc[4] = {};
#pragma unroll
    for (int k0 = 0; k0 < 64; k0 += 32) {
        bf16x8 a1 = *(const bf16x8*)&KS[(w * 16 + l15) * LDT + k0 + quad * 8];
        bf16x8 a2 = *(const bf16x8*)&Qs[(w * 16 + l15) * LDT + k0 + quad * 8];
#pragma unroll
        for (int tj = 0; tj < 4; ++tj) {
            const int rb = tj * 16 + l15;
            bf16x8 b1 = *(const bf16x8*)&VT[rb * LDT + ((k0 + quad * 8) ^ (rb & 56))];
            bf16x8 b2 = *(const bf16x8*)&KVT[rb * LDT + ((k0 + quad * 8) ^ (rb & 56))];
            oacc[tj] = __builtin_amdgcn_mfma_f32_16x16x32_bf16(a1, b1, oacc[tj], 0, 0, 0);
            oacc[tj] = __builtin_amdgcn_mfma_f32_16x16x32_bf16(a2, b2, oacc[tj], 0, 0, 0);
        }
    }
    const size_t arowbase = (size_t)b * 2048 + c * 64;   // attnb stays [b,t][h,e]
#pragma unroll
    for (int tj = 0; tj < 4; ++tj)
#pragma unroll
        for (int r = 0; r < 4; ++r) {
            const int i = w * 16 + quad * 4 + r;
            const int e = tj * 16 + l15;
            attnb[(arowbase + i) * 1024 + h * 64 + e] = f2bf(oacc[tj][r] * zinv[r]);
        }
}

// ---------------- Kernel 5: output projection GEMM (128x64, 3-buf) ---------
__global__ __launch_bounds__(256) void gemm_out(
    const short* __restrict__ attnb, const short* __restrict__ Wob,
    const float* __restrict__ bo, float* __restrict__ outp)
{
    __shared__ short As[3][128 * 32];
    __shared__ short Bs[3][64 * 32];
    const int tid = threadIdx.x;
    const int bm = blockIdx.x, bn = blockIdx.y;      // 32 x 16
    const int m0 = bm << 7, n0 = bn << 6;
    const int wave = tid >> 6, lane = tid & 63;
    const int wm = (wave & 1) << 6, wn = (wave >> 1) << 5;
    const int l15 = lane & 15, quad = lane >> 4;

    const int lrow = lane >> 2;
    const int lcol = (((lane & 3) ^ ((lane >> 3) & 3)) << 3);   // r15 swizzle
    const short* gp[3]; int lof[3]; bool isA[3];
#pragma unroll
    for (int cc = 0; cc < 3; ++cc) {
        const int ch = wave * 3 + cc;
        if (ch < 8) {
            gp[cc] = attnb + (size_t)(m0 + ch * 16 + lrow) * 1024 + lcol;
            lof[cc] = ch * 512;  isA[cc] = true;
        } else {
            gp[cc] = Wob + (size_t)(n0 + (ch - 8) * 16 + lrow) * 1024 + lcol;
            lof[cc] = (ch - 8) * 512;  isA[cc] = false;
        }
    }
    const int rslot = (quad ^ ((l15 >> 1) & 3)) << 3;           // r15 swizzle

#define OUT_STAGE(K, BUF)                                                   \
    do {                                                                    \
        _Pragma("unroll")                                                   \
        for (int cc = 0; cc < 3; ++cc)                                      \
            gl_lds16(gp[cc] + (K), (isA[cc] ? &As[BUF][lof[cc]]             \
                                            : &Bs[BUF][lof[cc]]));          \
    } while (0)

#define OUT_COMPUTE(BUF)                                                              \
    do {                                                                              \
        bf16x8 a[4], b[2];                                                            \
        _Pragma("unroll")                                                             \
        for (int i = 0; i < 4; ++i)                                                   \
            a[i] = *(const bf16x8*)&As[BUF][(wm + i * 16 + l15) * 32 + rslot];        \
        _Pragma("unroll")                                                             \
        for (int j = 0; j < 2; ++j)                                                   \
            b[j] = *(const bf16x8*)&Bs[BUF][(wn + j * 16 + l15) * 32 + rslot];        \
        _Pragma("unroll")                                                             \
        for (int i = 0; i < 4; ++i)                                                   \
            _Pragma("unroll")                                                         \
            for (int j = 0; j < 2; ++j)                                               \
                acc[i][j] = __builtin_amdgcn_mfma_f32_16x16x32_bf16(a[i], b[j],       \
                                                                   acc[i][j], 0, 0, 0); \
    } while (0)

#define OUT_STEP(T, RB, SB)                                   \
    do {                                                      \
        asm volatile("s_waitcnt vmcnt(3)" ::: "memory");      \
        __builtin_amdgcn_s_barrier();                         \
        __builtin_amdgcn_sched_barrier(0);                    \
        OUT_STAGE(((T) + 2) * 32, SB);                        \
        OUT_COMPUTE(RB);                                      \
    } while (0)

    f32x4 acc[4][2] = {};
    OUT_STAGE(0, 0);
    OUT_STAGE(32, 1);
    for (int u = 0; u < 10; ++u) {           // steps t = 0..29
        const int t = u * 3;
        OUT_STEP(t + 0, 0, 2);
        OUT_STEP(t + 1, 1, 0);
        OUT_STEP(t + 2, 2, 1);
    }
    // t = 30
    asm volatile("s_waitcnt vmcnt(3)" ::: "memory");
    __builtin_amdgcn_s_barrier();
    __builtin_amdgcn_sched_barrier(0);
    OUT_COMPUTE(0);
    // t = 31
    asm volatile("s_waitcnt vmcnt(0)" ::: "memory");
    __builtin_amdgcn_s_barrier();
    __builtin_amdgcn_sched_barrier(0);
    OUT_COMPUTE(1);
#undef OUT_STEP
#undef OUT_STAGE
#undef OUT_COMPUTE

#pragma unroll
    for (int i = 0; i < 4; ++i)
#pragma unroll
        for (int j = 0; j < 2; ++j) {
            const int col = n0 + wn + j * 16 + l15;
            const float bv_ = bo[col];
#pragma unroll
            for (int r = 0; r < 4; ++r) {
                const int row = m0 + wm + i * 16 + quad * 4 + r;
                outp[(size_t)row * 1024 + col] = acc[i][j][r] + bv_;
            }
        }
}

// ---------------------------------------------------------------------------
extern "C" void kernel_launch(void* const* d_in, const int* in_sizes, int n_in,
                              void* d_out, int out_size, void* d_ws, size_t ws_size,
                              hipStream_t stream)
{
    const float* x  = (const float*)d_in[0];
    const float* Wq = (const float*)d_in[1];
    const float* bq = (const float*)d_in[2];
    const float* Wk = (const float*)d_in[3];
    const float* bk = (const float*)d_in[4];
    const float* Wv = (const float*)d_in[5];
    const float* bv = (const float*)d_in[6];
    const float* Wo = (const float*)d_in[7];
    const float* bo = (const float*)d_in[8];

    char* ws = (char*)d_ws;
    short* xb     = (short*)(ws + 0);          //  8 MB [4096][1024] bf16
    short* Wqb    = (short*)(ws + 8388608);    //  2 MB
    short* Wkb    = (short*)(ws + 10485760);   //  2 MB
    short* Wvb    = (short*)(ws + 12582912);   //  2 MB
    short* Wob    = (short*)(ws + 14680064);   //  2 MB
    short* Qb     = (short*)(ws + 16777216);   //  8 MB [bh*2048+t][64]
    short* Kb     = (short*)(ws + 25165824);   //  8 MB [bh*2048+t][64]
    short* Vb     = (short*)(ws + 33554432);   //  8 MB [bh*2048+t][64]
    short* KVsum  = (short*)(ws + 41943040);   //  8 MB [bh][c][d*64+e] bf16
    short* KVpref = (short*)(ws + 50331648);   //  8 MB bf16, same layout
    short* attnb  = (short*)(ws + 58720256);   //  8 MB [b,t][h*64+e]
    float* ksum   = (float*)(ws + 67108864);   // 256 KB
    float* kpref  = (float*)(ws + 67371008);   // 256 KB
    float* outp   = (float*)d_out;

    convert_bf16<<<4096, 256, 0, stream>>>(x, Wq, Wk, Wv, Wo, xb, Wqb, Wkb, Wvb, Wob);
    gemm_qkv   <<<dim3(32, 24), 256, 0, stream>>>(xb, Wqb, Wkb, Wvb, bq, bk, bv, Qb, Kb, Vb);
    chunk_sums <<<dim3(32, 32), 256, 0, stream>>>(Kb, Vb, KVsum, ksum);
    scan_chunks<<<dim3(16, 32), 256, 0, stream>>>(KVsum, ksum, KVpref, kpref);
    attn_chunk <<<dim3(32, 32), 256, 0, stream>>>(Qb, Kb, Vb, KVpref, kpref, attnb);
    gemm_out   <<<dim3(32, 16), 256, 0, stream>>>(attnb, Wob, bo, outp);
}

// Round 10
// 170.869 us; speedup vs baseline: 1.6967x; 1.0488x over previous
//
#include <hip/hip_runtime.h>

// ---------------------------------------------------------------------------
// Linear attention (causal, phi = elu+1), B=2 T=2048 H=16 dk=64 D=1024.
// r19 (3-buf counted vmcnt + sched_barrier(0)): qkv 46->60us = the m141
// order-pinning regression; counted-vmcnt never actually tested.
// r20: same 3-buffer pipeline, but sched_barrier(0xF) = allow ALU|VALU|SALU|
// MFMA to cross, pin DS+VMEM. Keeps the two required orderings (ds_read
// after residency barrier; stage after reader barrier; epilogue VMEM out of
// the loop) while restoring compiler interleave. Each tile's loads get ~2
// compute phases (~700cy) of cover vs r16's ~1 phase (~350cy).
// ---------------------------------------------------------------------------

typedef float  f32x4   __attribute__((ext_vector_type(4)));
typedef __bf16 bf16x8  __attribute__((ext_vector_type(8)));
typedef short  short8v __attribute__((ext_vector_type(8)));
typedef short  short4v __attribute__((ext_vector_type(4)));

static __device__ __forceinline__ short f2bf(float f) {
    unsigned u = __float_as_uint(f);
    u += 0x7FFFu + ((u >> 16) & 1u);          // RNE
    return (short)(u >> 16);
}
static __device__ __forceinline__ float bf2f(short s) {
    return __uint_as_float(((unsigned)(unsigned short)s) << 16);
}
static __device__ __forceinline__ float phi(float x) {   // elu(x)+1
    return x > 0.f ? x + 1.f : __expf(x);
}
static __device__ __forceinline__ void gl_lds16(const short* g, short* l) {
    __builtin_amdgcn_global_load_lds(
        (const __attribute__((address_space(1))) void*)g,
        (__attribute__((address_space(3))) void*)l, 16, 0, 0);
}

#define LDT 72   // 64x64 tile leading dim
static __device__ __forceinline__ int swz(int row, int col) {
    return row * LDT + (col ^ (row & 56));
}

// sched_barrier mask: allow ALU(1)|VALU(2)|SALU(4)|MFMA(8); pin DS + VMEM.
#define SB_MASK 0xF

// ---------------- Kernel 0: fp32 -> bf16 conversion ------------------------
__global__ __launch_bounds__(256) void convert_bf16(
    const float* __restrict__ x,  const float* __restrict__ Wq,
    const float* __restrict__ Wk, const float* __restrict__ Wv,
    const float* __restrict__ Wo,
    short* __restrict__ xb,  short* __restrict__ Wqb,
    short* __restrict__ Wkb, short* __restrict__ Wvb, short* __restrict__ Wob)
{
    const int blk = blockIdx.x;
    const float* src; short* dst; size_t base;
    if (blk < 2048)      { src = x;  dst = xb;  base = (size_t)blk * 2048; }
    else if (blk < 2560) { src = Wq; dst = Wqb; base = (size_t)(blk - 2048) * 2048; }
    else if (blk < 3072) { src = Wk; dst = Wkb; base = (size_t)(blk - 2560) * 2048; }
    else if (blk < 3584) { src = Wv; dst = Wvb; base = (size_t)(blk - 3072) * 2048; }
    else                 { src = Wo; dst = Wob; base = (size_t)(blk - 3584) * 2048; }
    const size_t o = base + (size_t)threadIdx.x * 8;
    f32x4 v0 = *(const f32x4*)&src[o];
    f32x4 v1 = *(const f32x4*)&src[o + 4];
    short8v s;
#pragma unroll
    for (int m = 0; m < 4; ++m) { s[m] = f2bf(v0[m]); s[m + 4] = f2bf(v1[m]); }
    *(short8v*)&dst[o] = s;
}

// ---------------- Kernel 1: fused QKV GEMM (128x128, BK=32, 3-buf) ---------
// Output layout: [(b*16+h)*2048 + t][64] bf16 for Q, K, V.
__global__ __launch_bounds__(256) void gemm_qkv(
    const short* __restrict__ xb,
    const short* __restrict__ Wqb, const short* __restrict__ Wkb,
    const short* __restrict__ Wvb,
    const float* __restrict__ bq, const float* __restrict__ bk,
    const float* __restrict__ bv,
    short* __restrict__ Qb, short* __restrict__ Kb, short* __restrict__ Vb)
{
    __shared__ short As[3][128 * 32];
    __shared__ short Bs[3][128 * 32];
    const int tid = threadIdx.x;
    const int bm = blockIdx.x, bn = blockIdx.y;      // 32 x 24
    const int wsel = bn >> 3;                        // 0=Q 1=K 2=V
    const int n0 = (bn & 7) << 7;
    const short* __restrict__ W    = (wsel == 0) ? Wqb : (wsel == 1) ? Wkb : Wvb;
    const float* __restrict__ bias = (wsel == 0) ? bq  : (wsel == 1) ? bk  : bv;
    short* __restrict__ Ob         = (wsel == 0) ? Qb  : (wsel == 1) ? Kb  : Vb;
    const int m0 = bm << 7;
    const int wave = tid >> 6, lane = tid & 63;
    const int wm = (wave & 1) << 6, wn = (wave >> 1) << 6;
    const int l15 = lane & 15, quad = lane >> 4;

    const int ch0 = wave * 2, ch1 = ch0 + 1;
    const int lrow = lane >> 2;
    // r15 swizzle: slot (lane&3) receives k-slot (lane&3)^((lane>>3)&3)
    const int lcol = (((lane & 3) ^ ((lane >> 3) & 3)) << 3);
    const short* ga0 = xb + (size_t)(m0 + ch0 * 16 + lrow) * 1024 + lcol;
    const short* ga1 = xb + (size_t)(m0 + ch1 * 16 + lrow) * 1024 + lcol;
    const short* gb0 = W  + (size_t)(n0 + ch0 * 16 + lrow) * 1024 + lcol;
    const short* gb1 = W  + (size_t)(n0 + ch1 * 16 + lrow) * 1024 + lcol;
    const int lo0 = ch0 * 512, lo1 = ch1 * 512;
    // read-side slot for fragment row: (l15>>1)&3
    const int rslot = (quad ^ ((l15 >> 1) & 3)) << 3;

#define QKV_STAGE(K, BUF)                        \
    do {                                         \
        gl_lds16(ga0 + (K), &As[BUF][lo0]);      \
        gl_lds16(ga1 + (K), &As[BUF][lo1]);      \
        gl_lds16(gb0 + (K), &Bs[BUF][lo0]);      \
        gl_lds16(gb1 + (K), &Bs[BUF][lo1]);      \
    } while (0)

#define QKV_COMPUTE(BUF)                                                              \
    do {                                                                              \
        bf16x8 a[4], b[4];                                                            \
        _Pragma("unroll")                                                             \
        for (int i = 0; i < 4; ++i)                                                   \
            a[i] = *(const bf16x8*)&As[BUF][(wm + i * 16 + l15) * 32 + rslot];        \
        _Pragma("unroll")                                                             \
        for (int j = 0; j < 4; ++j)                                                   \
            b[j] = *(const bf16x8*)&Bs[BUF][(wn + j * 16 + l15) * 32 + rslot];        \
        _Pragma("unroll")                                                             \
        for (int i = 0; i < 4; ++i)                                                   \
            _Pragma("unroll")                                                         \
            for (int j = 0; j < 4; ++j)                                               \
                acc[i][j] = __builtin_amdgcn_mfma_f32_16x16x32_bf16(a[i], b[j],       \
                                                                   acc[i][j], 0, 0, 0); \
    } while (0)

// One K-step: wait own stage(T) drained (vmcnt(4) leaves only stage(T+1)
// in flight), barrier -> all waves' tile-T data resident; stage T+2 into
// the buffer compute(T-1) just vacated; compute tile T. sched_barrier(SB_MASK)
// pins DS+VMEM at the barrier but lets ALU/MFMA flow across.
#define QKV_STEP(T, RB, SB)                                   \
    do {                                                      \
        asm volatile("s_waitcnt vmcnt(4)" ::: "memory");      \
        __builtin_amdgcn_s_barrier();                         \
        __builtin_amdgcn_sched_barrier(SB_MASK);              \
        QKV_STAGE(((T) + 2) * 32, SB);                        \
        QKV_COMPUTE(RB);                                      \
    } while (0)

    f32x4 acc[4][4] = {};
    QKV_STAGE(0, 0);
    QKV_STAGE(32, 1);
    for (int u = 0; u < 10; ++u) {           // steps t = 3u .. 3u+2  (0..29)
        const int t = u * 3;
        QKV_STEP(t + 0, 0, 2);
        QKV_STEP(t + 1, 1, 0);
        QKV_STEP(t + 2, 2, 1);
    }
    // t = 30: stage(31) is the only remaining in-flight stage
    asm volatile("s_waitcnt vmcnt(4)" ::: "memory");
    __builtin_amdgcn_s_barrier();
    __builtin_amdgcn_sched_barrier(SB_MASK);
    QKV_COMPUTE(0);
    // t = 31: drain everything
    asm volatile("s_waitcnt vmcnt(0)" ::: "memory");
    __builtin_amdgcn_s_barrier();
    __builtin_amdgcn_sched_barrier(SB_MASK);
    QKV_COMPUTE(1);
#undef QKV_STEP
#undef QKV_STAGE
#undef QKV_COMPUTE

#pragma unroll
    for (int i = 0; i < 4; ++i)
#pragma unroll
        for (int j = 0; j < 4; ++j) {
            const int col = n0 + wn + j * 16 + l15;     // h*64 + d
            const int h = col >> 6, d = col & 63;
            const float bv_ = bias[col];
            const int row0 = m0 + wm + i * 16 + quad * 4;   // b*2048 + t0
            const int b = row0 >> 11, t0 = row0 & 2047;
            const size_t obase = ((size_t)(b * 16 + h) * 2048 + t0) * 64 + d;
#pragma unroll
            for (int r = 0; r < 4; ++r) {
                float v = acc[i][j][r] + bv_;
                if (wsel < 2) v = phi(v);
                Ob[obase + (size_t)r * 64] = f2bf(v);
            }
        }
}

// ---------------- Kernel 2: per-chunk KV state: KV_c = K_c^T V_c, ksum_c ---
__global__ __launch_bounds__(256) void chunk_sums(
    const short* __restrict__ Kb, const short* __restrict__ Vb,
    short* __restrict__ KVsum, float* __restrict__ ksum)
{
    __shared__ short KT[64 * LDT];   // K^T : [d][t]  (swizzled cols)
    __shared__ short VT[64 * LDT];   // V^T : [e][t]  (swizzled cols)
    __shared__ float pS[256];
    const int c = blockIdx.x, bh = blockIdx.y;
    const int tid = threadIdx.x;
    const int w = tid >> 6, lane = tid & 63, l15 = lane & 15, quad = lane >> 4;
    const size_t tilebase = ((size_t)bh * 2048 + c * 64) * 64;

#pragma unroll
    for (int p = 0; p < 2; ++p) {
        const int t = (tid >> 3) + p * 32;
        const int e0 = (tid & 7) << 3;
        const size_t g = tilebase + (size_t)t * 64 + e0;   // contiguous 4KB span
        short8v kv = *(const short8v*)&Kb[g];
        short8v vv = *(const short8v*)&Vb[g];
#pragma unroll
        for (int jj = 0; jj < 8; ++jj) {
            KT[swz(e0 + jj, t)] = kv[jj];
            VT[swz(e0 + jj, t)] = vv[jj];
        }
    }
    __syncthreads();

    f32x4 acc[4] = {};
#pragma unroll
    for (int k0 = 0; k0 < 64; k0 += 32) {
        const int ra = w * 16 + l15;
        bf16x8 a = *(const bf16x8*)&KT[ra * LDT + ((k0 + quad * 8) ^ (ra & 56))];
#pragma unroll
        for (int tj = 0; tj < 4; ++tj) {
            const int rb = tj * 16 + l15;
            bf16x8 bfr = *(const bf16x8*)&VT[rb * LDT + ((k0 + quad * 8) ^ (rb & 56))];
            acc[tj] = __builtin_amdgcn_mfma_f32_16x16x32_bf16(a, bfr, acc[tj], 0, 0, 0);
        }
    }
    short* __restrict__ outp = KVsum + (((size_t)bh * 32) + c) * 4096;   // [d][e]
#pragma unroll
    for (int tj = 0; tj < 4; ++tj)
#pragma unroll
        for (int r = 0; r < 4; ++r)
            outp[(w * 16 + quad * 4 + r) * 64 + tj * 16 + l15] = f2bf(acc[tj][r]);

    {   // ksum partials: thread = (part, d)
        const int d = tid & 63, part = tid >> 6;
        short8v k1 = *(const short8v*)&KT[d * LDT + ((part * 16) ^ (d & 56))];
        short8v k2 = *(const short8v*)&KT[d * LDT + ((part * 16 + 8) ^ (d & 56))];
        float s = 0.f;
#pragma unroll
        for (int m = 0; m < 8; ++m) s += bf2f(k1[m]) + bf2f(k2[m]);
        pS[part * 64 + d] = s;
    }
    __syncthreads();
    if (tid < 64)
        ksum[(((size_t)bh * 32) + c) * 64 + tid] =
            pS[tid] + pS[tid + 64] + pS[tid + 128] + pS[tid + 192];
}

// ---------------- Kernel 3: exclusive prefix scan over 32 chunks -----------
__global__ __launch_bounds__(256) void scan_chunks(
    const short* __restrict__ KVsum, const float* __restrict__ ksum,
    short* __restrict__ KVpref, float* __restrict__ kpref)
{
    const int bh = blockIdx.y;
    const int o = blockIdx.x * 256 + threadIdx.x;     // 16 x 256 = 4096
    const size_t base = (size_t)bh * 32 * 4096 + o;
    short v[32];
#pragma unroll
    for (int cc = 0; cc < 32; ++cc) v[cc] = KVsum[base + (size_t)cc * 4096];
    float run = 0.f;
#pragma unroll
    for (int cc = 0; cc < 32; ++cc) {
        KVpref[base + (size_t)cc * 4096] = f2bf(run);   // exclusive
        run += bf2f(v[cc]);
    }
    if (blockIdx.x == 0 && threadIdx.x < 64) {
        float vals[32];
        const size_t kb = (size_t)bh * 32 * 64 + threadIdx.x;
#pragma unroll
        for (int cc = 0; cc < 32; ++cc) vals[cc] = ksum[kb + (size_t)cc * 64];
        float r2 = 0.f;
#pragma unroll
        for (int cc = 0; cc < 32; ++cc) { kpref[kb + (size_t)cc * 64] = r2; r2 += vals[cc]; }
    }
}

// ---------------- Kernel 4: per-chunk attention ----------------------------
__global__ __launch_bounds__(256) void attn_chunk(
    const short* __restrict__ Qb, const short* __restrict__ Kb,
    const short* __restrict__ Vb, const short* __restrict__ KVpref,
    const float* __restrict__ kpref, short* __restrict__ attnb)
{
    __shared__ short Qs[64 * LDT];
    __shared__ short KS[64 * LDT];   // K, then overwritten with masked S (straight)
    __shared__ short VT[64 * LDT];   // V^T  [e][t]  (swizzled)
    __shared__ short KVT[64 * LDT];  // KVpref^T [e][d]  (swizzled)
    const int c = blockIdx.x, bh = blockIdx.y;
    const int b = bh >> 4, h = bh & 15;
    const int tid = threadIdx.x;
    const int w = tid >> 6, lane = tid & 63, l15 = lane & 15, quad = lane >> 4;
    const size_t tilebase = ((size_t)bh * 2048 + c * 64) * 64;
    const short* __restrict__ KVc = KVpref + (((size_t)bh * 32) + c) * 4096;

#pragma unroll
    for (int p = 0; p < 2; ++p) {
        const int t = (tid >> 3) + p * 32;             // t for Q/K/V; d for KVpref
        const int e0 = (tid & 7) << 3;
        const size_t g = tilebase + (size_t)t * 64 + e0;  // contiguous 4KB span
        *(short8v*)&Qs[t * LDT + e0] = *(const short8v*)&Qb[g];
        *(short8v*)&KS[t * LDT + e0] = *(const short8v*)&Kb[g];
        short8v vv = *(const short8v*)&Vb[g];
        short8v pv = *(const short8v*)&KVc[t * 64 + e0];
#pragma unroll
        for (int jj = 0; jj < 8; ++jj) {
            VT[swz(e0 + jj, t)]  = vv[jj];
            KVT[swz(e0 + jj, t)] = pv[jj];
        }
    }
    __syncthreads();

    // ---- S = Q K^T ---------------------------------------------------------
    f32x4 sacc[4] = {};
#pragma unroll
    for (int k0 = 0; k0 < 64; k0 += 32) {
        bf16x8 a = *(const bf16x8*)&Qs[(w * 16 + l15) * LDT + k0 + quad * 8];
#pragma unroll
        for (int tj = 0; tj < 4; ++tj) {
            bf16x8 bfr = *(const bf16x8*)&KS[(tj * 16 + l15) * LDT + k0 + quad * 8];
            sacc[tj] = __builtin_amdgcn_mfma_f32_16x16x32_bf16(a, bfr, sacc[tj], 0, 0, 0);
        }
    }

    // ---- z via masked rowsum + q.kpref, 16-lane butterfly ------------------
    f32x4 kp4 = *(const f32x4*)&kpref[(((size_t)bh * 32) + c) * 64 + l15 * 4];
    float zinv[4];
#pragma unroll
    for (int r = 0; r < 4; ++r) {
        const int i = w * 16 + quad * 4 + r;
        float p = 0.f;
#pragma unroll
        for (int tj = 0; tj < 4; ++tj)
            if (tj * 16 + l15 <= i) p += sacc[tj][r];
        short4v q4 = *(const short4v*)&Qs[i * LDT + l15 * 4];
#pragma unroll
        for (int m = 0; m < 4; ++m) p += bf2f(q4[m]) * kp4[m];
        p += __shfl_xor(p, 1);
        p += __shfl_xor(p, 2);
        p += __shfl_xor(p, 4);
        p += __shfl_xor(p, 8);
        zinv[r] = 1.f / (p + 1e-6f);
    }

    __syncthreads();   // all waves done reading KS-as-K before overwrite
#pragma unroll
    for (int tj = 0; tj < 4; ++tj)
#pragma unroll
        for (int r = 0; r < 4; ++r) {
            const int i = w * 16 + quad * 4 + r;
            const int j = tj * 16 + l15;
            KS[i * LDT + j] = f2bf(j <= i ? sacc[tj][r] : 0.f);
        }
    // NO barrier: O-MFMA a1 reads KS rows [w*16, w*16+16) - wave-private.

    // ---- O = causal(S) V + Q KVpref ---------------------------------------
    f32x4 oacc[4] = {};
#pragma unroll
    for (int k0 = 0; k0 < 64; k0 += 32) {
        bf16x8 a1 = *(const bf16x8*)&KS[(w * 16 + l15) * LDT + k0 + quad * 8];
        bf16x8 a2 = *(const bf16x8*)&Qs[(w * 16 + l15) * LDT + k0 + quad * 8];
#pragma unroll
        for (int tj = 0; tj < 4; ++tj) {
            const int rb = tj * 16 + l15;
            bf16x8 b1 = *(const bf16x8*)&VT[rb * LDT + ((k0 + quad * 8) ^ (rb & 56))];
            bf16x8 b2 = *(const bf16x8*)&KVT[rb * LDT + ((k0 + quad * 8) ^ (rb & 56))];
            oacc[tj] = __builtin_amdgcn_mfma_f32_16x16x32_bf16(a1, b1, oacc[tj], 0, 0, 0);
            oacc[tj] = __builtin_amdgcn_mfma_f32_16x16x32_bf16(a2, b2, oacc[tj], 0, 0, 0);
        }
    }
    const size_t arowbase = (size_t)b * 2048 + c * 64;   // attnb stays [b,t][h,e]
#pragma unroll
    for (int tj = 0; tj < 4; ++tj)
#pragma unroll
        for (int r = 0; r < 4; ++r) {
            const int i = w * 16 + quad * 4 + r;
            const int e = tj * 16 + l15;
            attnb[(arowbase + i) * 1024 + h * 64 + e] = f2bf(oacc[tj][r] * zinv[r]);
        }
}

// ---------------- Kernel 5: output projection GEMM (128x64, 3-buf) ---------
__global__ __launch_bounds__(256) void gemm_out(
    const short* __restrict__ attnb, const short* __restrict__ Wob,
    const float* __restrict__ bo, float* __restrict__ outp)
{
    __shared__ short As[3][128 * 32];
    __shared__ short Bs[3][64 * 32];
    const int tid = threadIdx.x;
    const int bm = blockIdx.x, bn = blockIdx.y;      // 32 x 16
    const int m0 = bm << 7, n0 = bn << 6;
    const int wave = tid >> 6, lane = tid & 63;
    const int wm = (wave & 1) << 6, wn = (wave >> 1) << 5;
    const int l15 = lane & 15, quad = lane >> 4;

    const int lrow = lane >> 2;
    const int lcol = (((lane & 3) ^ ((lane >> 3) & 3)) << 3);   // r15 swizzle
    const short* gp[3]; int lof[3]; bool isA[3];
#pragma unroll
    for (int cc = 0; cc < 3; ++cc) {
        const int ch = wave * 3 + cc;
        if (ch < 8) {
            gp[cc] = attnb + (size_t)(m0 + ch * 16 + lrow) * 1024 + lcol;
            lof[cc] = ch * 512;  isA[cc] = true;
        } else {
            gp[cc] = Wob + (size_t)(n0 + (ch - 8) * 16 + lrow) * 1024 + lcol;
            lof[cc] = (ch - 8) * 512;  isA[cc] = false;
        }
    }
    const int rslot = (quad ^ ((l15 >> 1) & 3)) << 3;           // r15 swizzle

#define OUT_STAGE(K, BUF)                                                   \
    do {                                                                    \
        _Pragma("unroll")                                                   \
        for (int cc = 0; cc < 3; ++cc)                                      \
            gl_lds16(gp[cc] + (K), (isA[cc] ? &As[BUF][lof[cc]]             \
                                            : &Bs[BUF][lof[cc]]));          \
    } while (0)

#define OUT_COMPUTE(BUF)                                                              \
    do {                                                                              \
        bf16x8 a[4], b[2];                                                            \
        _Pragma("unroll")                                                             \
        for (int i = 0; i < 4; ++i)                                                   \
            a[i] = *(const bf16x8*)&As[BUF][(wm + i * 16 + l15) * 32 + rslot];        \
        _Pragma("unroll")                                                             \
        for (int j = 0; j < 2; ++j)                                                   \
            b[j] = *(const bf16x8*)&Bs[BUF][(wn + j * 16 + l15) * 32 + rslot];        \
        _Pragma("unroll")                                                             \
        for (int i = 0; i < 4; ++i)                                                   \
            _Pragma("unroll")                                                         \
            for (int j = 0; j < 2; ++j)                                               \
                acc[i][j] = __builtin_amdgcn_mfma_f32_16x16x32_bf16(a[i], b[j],       \
                                                                   acc[i][j], 0, 0, 0); \
    } while (0)

#define OUT_STEP(T, RB, SB)                                   \
    do {                                                      \
        asm volatile("s_waitcnt vmcnt(3)" ::: "memory");      \
        __builtin_amdgcn_s_barrier();                         \
        __builtin_amdgcn_sched_barrier(SB_MASK);              \
        OUT_STAGE(((T) + 2) * 32, SB);                        \
        OUT_COMPUTE(RB);                                      \
    } while (0)

    f32x4 acc[4][2] = {};
    OUT_STAGE(0, 0);
    OUT_STAGE(32, 1);
    for (int u = 0; u < 10; ++u) {           // steps t = 0..29
        const int t = u * 3;
        OUT_STEP(t + 0, 0, 2);
        OUT_STEP(t + 1, 1, 0);
        OUT_STEP(t + 2, 2, 1);
    }
    // t = 30
    asm volatile("s_waitcnt vmcnt(3)" ::: "memory");
    __builtin_amdgcn_s_barrier();
    __builtin_amdgcn_sched_barrier(SB_MASK);
    OUT_COMPUTE(0);
    // t = 31
    asm volatile("s_waitcnt vmcnt(0)" ::: "memory");
    __builtin_amdgcn_s_barrier();
    __builtin_amdgcn_sched_barrier(SB_MASK);
    OUT_COMPUTE(1);
#undef OUT_STEP
#undef OUT_STAGE
#undef OUT_COMPUTE

#pragma unroll
    for (int i = 0; i < 4; ++i)
#pragma unroll
        for (int j = 0; j < 2; ++j) {
            const int col = n0 + wn + j * 16 + l15;
            const float bv_ = bo[col];
#pragma unroll
            for (int r = 0; r < 4; ++r) {
                const int row = m0 + wm + i * 16 + quad * 4 + r;
                outp[(size_t)row * 1024 + col] = acc[i][j][r] + bv_;
            }
        }
}

// ---------------------------------------------------------------------------
extern "C" void kernel_launch(void* const* d_in, const int* in_sizes, int n_in,
                              void* d_out, int out_size, void* d_ws, size_t ws_size,
                              hipStream_t stream)
{
    const float* x  = (const float*)d_in[0];
    const float* Wq = (const float*)d_in[1];
    const float* bq = (const float*)d_in[2];
    const float* Wk = (const float*)d_in[3];
    const float* bk = (const float*)d_in[4];
    const float* Wv = (const float*)d_in[5];
    const float* bv = (const float*)d_in[6];
    const float* Wo = (const float*)d_in[7];
    const float* bo = (const float*)d_in[8];

    char* ws = (char*)d_ws;
    short* xb     = (short*)(ws + 0);          //  8 MB [4096][1024] bf16
    short* Wqb    = (short*)(ws + 8388608);    //  2 MB
    short* Wkb    = (short*)(ws + 10485760);   //  2 MB
    short* Wvb    = (short*)(ws + 12582912);   //  2 MB
    short* Wob    = (short*)(ws + 14680064);   //  2 MB
    short* Qb     = (short*)(ws + 16777216);   //  8 MB [bh*2048+t][64]
    short* Kb     = (short*)(ws + 25165824);   //  8 MB [bh*2048+t][64]
    short* Vb     = (short*)(ws + 33554432);   //  8 MB [bh*2048+t][64]
    short* KVsum  = (short*)(ws + 41943040);   //  8 MB [bh][c][d*64+e] bf16
    short* KVpref = (short*)(ws + 50331648);   //  8 MB bf16, same layout
    short* attnb  = (short*)(ws + 58720256);   //  8 MB [b,t][h*64+e]
    float* ksum   = (float*)(ws + 67108864);   // 256 KB
    float* kpref  = (float*)(ws + 67371008);   // 256 KB
    float* outp   = (float*)d_out;

    convert_bf16<<<4096, 256, 0, stream>>>(x, Wq, Wk, Wv, Wo, xb, Wqb, Wkb, Wvb, Wob);
    gemm_qkv   <<<dim3(32, 24), 256, 0, stream>>>(xb, Wqb, Wkb, Wvb, bq, bk, bv, Qb, Kb, Vb);
    chunk_sums <<<dim3(32, 32), 256, 0, stream>>>(Kb, Vb, KVsum, ksum);
    scan_chunks<<<dim3(16, 32), 256, 0, stream>>>(KVsum, ksum, KVpref, kpref);
    attn_chunk <<<dim3(32, 32), 256, 0, stream>>>(Qb, Kb, Vb, KVpref, kpref, attnb);
    gemm_out   <<<dim3(32, 16), 256, 0, stream>>>(attnb, Wob, bo, outp);
}

// Round 11
// 156.791 us; speedup vs baseline: 1.8490x; 1.0898x over previous
//
#include <hip/hip_runtime.h>

// ---------------------------------------------------------------------------
// Linear attention (causal, phi = elu+1), B=2 T=2048 H=16 dk=64 D=1024.
// FINAL (r21) = r15, the best-measured configuration (159.25us).
// Session findings baked in:
//  - k-slot XOR swizzle (r15): both-sides-or-neither with global_load_lds;
//    SQ_LDS_BANK_CONFLICT 9.4M -> 0, VGPR 112->80.
//  - scan preloads 32 values before the serial scan (r13, neutral-safe).
//  - Deeper pipelining of the 128^2/4-wave GEMMs does NOT pay:
//    r16 2-phase (~neutral total), r19 3-buf+sched_barrier(0) (-29% qkv,
//    m141-class regression), r20 3-buf+mask 0xF (still -9% vs r16).
//  - Fusion dead ends: hipLaunchCooperativeKernel not graph-capturable
//    (r17); software grid barrier costs L2 wb/inv per block per phase
//    (r18, 230us mega) but measured the ~60us harness fixed floor.
//  - Budget: ~60us fixed + ~84us kernels; qkv ~46us @ MfmaUtil 21% is the
//    only meaningful headroom and requires the 256^2/8-phase template.
// ---------------------------------------------------------------------------

typedef float  f32x4   __attribute__((ext_vector_type(4)));
typedef __bf16 bf16x8  __attribute__((ext_vector_type(8)));
typedef short  short8v __attribute__((ext_vector_type(8)));
typedef short  short4v __attribute__((ext_vector_type(4)));

static __device__ __forceinline__ short f2bf(float f) {
    unsigned u = __float_as_uint(f);
    u += 0x7FFFu + ((u >> 16) & 1u);          // RNE
    return (short)(u >> 16);
}
static __device__ __forceinline__ float bf2f(short s) {
    return __uint_as_float(((unsigned)(unsigned short)s) << 16);
}
static __device__ __forceinline__ float phi(float x) {   // elu(x)+1
    return x > 0.f ? x + 1.f : __expf(x);
}
static __device__ __forceinline__ void gl_lds16(const short* g, short* l) {
    __builtin_amdgcn_global_load_lds(
        (const __attribute__((address_space(1))) void*)g,
        (__attribute__((address_space(3))) void*)l, 16, 0, 0);
}

#define LDT 72   // 64x64 tile leading dim
static __device__ __forceinline__ int swz(int row, int col) {
    return row * LDT + (col ^ (row & 56));
}

// ---------------- Kernel 0: fp32 -> bf16 conversion ------------------------
__global__ __launch_bounds__(256) void convert_bf16(
    const float* __restrict__ x,  const float* __restrict__ Wq,
    const float* __restrict__ Wk, const float* __restrict__ Wv,
    const float* __restrict__ Wo,
    short* __restrict__ xb,  short* __restrict__ Wqb,
    short* __restrict__ Wkb, short* __restrict__ Wvb, short* __restrict__ Wob)
{
    const int blk = blockIdx.x;
    const float* src; short* dst; size_t base;
    if (blk < 2048)      { src = x;  dst = xb;  base = (size_t)blk * 2048; }
    else if (blk < 2560) { src = Wq; dst = Wqb; base = (size_t)(blk - 2048) * 2048; }
    else if (blk < 3072) { src = Wk; dst = Wkb; base = (size_t)(blk - 2560) * 2048; }
    else if (blk < 3584) { src = Wv; dst = Wvb; base = (size_t)(blk - 3072) * 2048; }
    else                 { src = Wo; dst = Wob; base = (size_t)(blk - 3584) * 2048; }
    const size_t o = base + (size_t)threadIdx.x * 8;
    f32x4 v0 = *(const f32x4*)&src[o];
    f32x4 v1 = *(const f32x4*)&src[o + 4];
    short8v s;
#pragma unroll
    for (int m = 0; m < 4; ++m) { s[m] = f2bf(v0[m]); s[m + 4] = f2bf(v1[m]); }
    *(short8v*)&dst[o] = s;
}

// ---------------- Kernel 1: fused QKV GEMM (m97, 128x128, BK=32) -----------
// Output layout: [(b*16+h)*2048 + t][64] bf16 for Q, K, V.
// k-slot XOR swizzle: LDS slot (row, s) holds global k-slot s ^ ((row>>1)&3);
// staged by permuting the SOURCE address (dest linear, rule 21).
__global__ __launch_bounds__(256) void gemm_qkv(
    const short* __restrict__ xb,
    const short* __restrict__ Wqb, const short* __restrict__ Wkb,
    const short* __restrict__ Wvb,
    const float* __restrict__ bq, const float* __restrict__ bk,
    const float* __restrict__ bv,
    short* __restrict__ Qb, short* __restrict__ Kb, short* __restrict__ Vb)
{
    __shared__ short As[128 * 32];
    __shared__ short Bs[128 * 32];
    const int tid = threadIdx.x;
    const int bm = blockIdx.x, bn = blockIdx.y;      // 32 x 24
    const int wsel = bn >> 3;                        // 0=Q 1=K 2=V
    const int n0 = (bn & 7) << 7;
    const short* __restrict__ W    = (wsel == 0) ? Wqb : (wsel == 1) ? Wkb : Wvb;
    const float* __restrict__ bias = (wsel == 0) ? bq  : (wsel == 1) ? bk  : bv;
    short* __restrict__ Ob         = (wsel == 0) ? Qb  : (wsel == 1) ? Kb  : Vb;
    const int m0 = bm << 7;
    const int wave = tid >> 6, lane = tid & 63;
    const int wm = (wave & 1) << 6, wn = (wave >> 1) << 6;
    const int l15 = lane & 15, quad = lane >> 4;

    const int ch0 = wave * 2, ch1 = ch0 + 1;
    const int lrow = lane >> 2;
    // source k-offset permuted: slot (lane&3) receives k-slot (lane&3)^((lane>>3)&3)
    const int lcol = (((lane & 3) ^ ((lane >> 3) & 3)) << 3);
    const short* ga0 = xb + (size_t)(m0 + ch0 * 16 + lrow) * 1024 + lcol;
    const short* ga1 = xb + (size_t)(m0 + ch1 * 16 + lrow) * 1024 + lcol;
    const short* gb0 = W  + (size_t)(n0 + ch0 * 16 + lrow) * 1024 + lcol;
    const short* gb1 = W  + (size_t)(n0 + ch1 * 16 + lrow) * 1024 + lcol;
    short* la0 = &As[ch0 * 512];
    short* la1 = &As[ch1 * 512];
    short* lb0 = &Bs[ch0 * 512];
    short* lb1 = &Bs[ch1 * 512];

    // read-side slot for fragment row (row>>1)&3 == (l15>>1)&3
    const int rslot = (quad ^ ((l15 >> 1) & 3)) << 3;

    f32x4 acc[4][4] = {};
    for (int k0 = 0; k0 < 1024; k0 += 32) {
        __syncthreads();
        gl_lds16(ga0 + k0, la0);
        gl_lds16(ga1 + k0, la1);
        gl_lds16(gb0 + k0, lb0);
        gl_lds16(gb1 + k0, lb1);
        __syncthreads();
        bf16x8 a[4], b[4];
#pragma unroll
        for (int i = 0; i < 4; ++i) a[i] = *(const bf16x8*)&As[(wm + i * 16 + l15) * 32 + rslot];
#pragma unroll
        for (int j = 0; j < 4; ++j) b[j] = *(const bf16x8*)&Bs[(wn + j * 16 + l15) * 32 + rslot];
#pragma unroll
        for (int i = 0; i < 4; ++i)
#pragma unroll
            for (int j = 0; j < 4; ++j)
                acc[i][j] = __builtin_amdgcn_mfma_f32_16x16x32_bf16(a[i], b[j], acc[i][j], 0, 0, 0);
    }

#pragma unroll
    for (int i = 0; i < 4; ++i)
#pragma unroll
        for (int j = 0; j < 4; ++j) {
            const int col = n0 + wn + j * 16 + l15;     // h*64 + d
            const int h = col >> 6, d = col & 63;
            const float bv_ = bias[col];
            const int row0 = m0 + wm + i * 16 + quad * 4;   // b*2048 + t0
            const int b = row0 >> 11, t0 = row0 & 2047;
            const size_t obase = ((size_t)(b * 16 + h) * 2048 + t0) * 64 + d;
#pragma unroll
            for (int r = 0; r < 4; ++r) {
                float v = acc[i][j][r] + bv_;
                if (wsel < 2) v = phi(v);
                Ob[obase + (size_t)r * 64] = f2bf(v);
            }
        }
}

// ---------------- Kernel 2: per-chunk KV state: KV_c = K_c^T V_c, ksum_c ---
__global__ __launch_bounds__(256) void chunk_sums(
    const short* __restrict__ Kb, const short* __restrict__ Vb,
    short* __restrict__ KVsum, float* __restrict__ ksum)
{
    __shared__ short KT[64 * LDT];   // K^T : [d][t]  (swizzled cols)
    __shared__ short VT[64 * LDT];   // V^T : [e][t]  (swizzled cols)
    __shared__ float pS[256];
    const int c = blockIdx.x, bh = blockIdx.y;
    const int tid = threadIdx.x;
    const int w = tid >> 6, lane = tid & 63, l15 = lane & 15, quad = lane >> 4;
    const size_t tilebase = ((size_t)bh * 2048 + c * 64) * 64;

#pragma unroll
    for (int p = 0; p < 2; ++p) {
        const int t = (tid >> 3) + p * 32;
        const int e0 = (tid & 7) << 3;
        const size_t g = tilebase + (size_t)t * 64 + e0;   // contiguous 4KB span
        short8v kv = *(const short8v*)&Kb[g];
        short8v vv = *(const short8v*)&Vb[g];
#pragma unroll
        for (int jj = 0; jj < 8; ++jj) {
            KT[swz(e0 + jj, t)] = kv[jj];
            VT[swz(e0 + jj, t)] = vv[jj];
        }
    }
    __syncthreads();

    f32x4 acc[4] = {};
#pragma unroll
    for (int k0 = 0; k0 < 64; k0 += 32) {
        const int ra = w * 16 + l15;
        bf16x8 a = *(const bf16x8*)&KT[ra * LDT + ((k0 + quad * 8) ^ (ra & 56))];
#pragma unroll
        for (int tj = 0; tj < 4; ++tj) {
            const int rb = tj * 16 + l15;
            bf16x8 bfr = *(const bf16x8*)&VT[rb * LDT + ((k0 + quad * 8) ^ (rb & 56))];
            acc[tj] = __builtin_amdgcn_mfma_f32_16x16x32_bf16(a, bfr, acc[tj], 0, 0, 0);
        }
    }
    short* __restrict__ outp = KVsum + (((size_t)bh * 32) + c) * 4096;   // [d][e]
#pragma unroll
    for (int tj = 0; tj < 4; ++tj)
#pragma unroll
        for (int r = 0; r < 4; ++r)
            outp[(w * 16 + quad * 4 + r) * 64 + tj * 16 + l15] = f2bf(acc[tj][r]);

    {   // ksum partials: thread = (part, d)
        const int d = tid & 63, part = tid >> 6;
        short8v k1 = *(const short8v*)&KT[d * LDT + ((part * 16) ^ (d & 56))];
        short8v k2 = *(const short8v*)&KT[d * LDT + ((part * 16 + 8) ^ (d & 56))];
        float s = 0.f;
#pragma unroll
        for (int m = 0; m < 8; ++m) s += bf2f(k1[m]) + bf2f(k2[m]);
        pS[part * 64 + d] = s;
    }
    __syncthreads();
    if (tid < 64)
        ksum[(((size_t)bh * 32) + c) * 64 + tid] =
            pS[tid] + pS[tid + 64] + pS[tid + 128] + pS[tid + 192];
}

// ---------------- Kernel 3: exclusive prefix scan over 32 chunks -----------
__global__ __launch_bounds__(256) void scan_chunks(
    const short* __restrict__ KVsum, const float* __restrict__ ksum,
    short* __restrict__ KVpref, float* __restrict__ kpref)
{
    const int bh = blockIdx.y;
    const int o = blockIdx.x * 256 + threadIdx.x;     // 16 x 256 = 4096
    const size_t base = (size_t)bh * 32 * 4096 + o;
    short v[32];
#pragma unroll
    for (int cc = 0; cc < 32; ++cc) v[cc] = KVsum[base + (size_t)cc * 4096];
    float run = 0.f;
#pragma unroll
    for (int cc = 0; cc < 32; ++cc) {
        KVpref[base + (size_t)cc * 4096] = f2bf(run);   // exclusive
        run += bf2f(v[cc]);
    }
    if (blockIdx.x == 0 && threadIdx.x < 64) {
        float vals[32];
        const size_t kb = (size_t)bh * 32 * 64 + threadIdx.x;
#pragma unroll
        for (int cc = 0; cc < 32; ++cc) vals[cc] = ksum[kb + (size_t)cc * 64];
        float r2 = 0.f;
#pragma unroll
        for (int cc = 0; cc < 32; ++cc) { kpref[kb + (size_t)cc * 64] = r2; r2 += vals[cc]; }
    }
}

// ---------------- Kernel 4: per-chunk attention ----------------------------
__global__ __launch_bounds__(256) void attn_chunk(
    const short* __restrict__ Qb, const short* __restrict__ Kb,
    const short* __restrict__ Vb, const short* __restrict__ KVpref,
    const float* __restrict__ kpref, short* __restrict__ attnb)
{
    __shared__ short Qs[64 * LDT];
    __shared__ short KS[64 * LDT];   // K, then overwritten with masked S (straight)
    __shared__ short VT[64 * LDT];   // V^T  [e][t]  (swizzled)
    __shared__ short KVT[64 * LDT];  // KVpref^T [e][d]  (swizzled)
    const int c = blockIdx.x, bh = blockIdx.y;
    const int b = bh >> 4, h = bh & 15;
    const int tid = threadIdx.x;
    const int w = tid >> 6, lane = tid & 63, l15 = lane & 15, quad = lane >> 4;
    const size_t tilebase = ((size_t)bh * 2048 + c * 64) * 64;
    const short* __restrict__ KVc = KVpref + (((size_t)bh * 32) + c) * 4096;

#pragma unroll
    for (int p = 0; p < 2; ++p) {
        const int t = (tid >> 3) + p * 32;             // t for Q/K/V; d for KVpref
        const int e0 = (tid & 7) << 3;
        const size_t g = tilebase + (size_t)t * 64 + e0;  // contiguous 4KB span
        *(short8v*)&Qs[t * LDT + e0] = *(const short8v*)&Qb[g];
        *(short8v*)&KS[t * LDT + e0] = *(const short8v*)&Kb[g];
        short8v vv = *(const short8v*)&Vb[g];
        short8v pv = *(const short8v*)&KVc[t * 64 + e0];
#pragma unroll
        for (int jj = 0; jj < 8; ++jj) {
            VT[swz(e0 + jj, t)]  = vv[jj];
            KVT[swz(e0 + jj, t)] = pv[jj];
        }
    }
    __syncthreads();

    // ---- S = Q K^T ---------------------------------------------------------
    f32x4 sacc[4] = {};
#pragma unroll
    for (int k0 = 0; k0 < 64; k0 += 32) {
        bf16x8 a = *(const bf16x8*)&Qs[(w * 16 + l15) * LDT + k0 + quad * 8];
#pragma unroll
        for (int tj = 0; tj < 4; ++tj) {
            bf16x8 bfr = *(const bf16x8*)&KS[(tj * 16 + l15) * LDT + k0 + quad * 8];
            sacc[tj] = __builtin_amdgcn_mfma_f32_16x16x32_bf16(a, bfr, sacc[tj], 0, 0, 0);
        }
    }

    // ---- z via masked rowsum + q.kpref, 16-lane butterfly ------------------
    f32x4 kp4 = *(const f32x4*)&kpref[(((size_t)bh * 32) + c) * 64 + l15 * 4];
    float zinv[4];
#pragma unroll
    for (int r = 0; r < 4; ++r) {
        const int i = w * 16 + quad * 4 + r;
        float p = 0.f;
#pragma unroll
        for (int tj = 0; tj < 4; ++tj)
            if (tj * 16 + l15 <= i) p += sacc[tj][r];
        short4v q4 = *(const short4v*)&Qs[i * LDT + l15 * 4];
#pragma unroll
        for (int m = 0; m < 4; ++m) p += bf2f(q4[m]) * kp4[m];
        p += __shfl_xor(p, 1);
        p += __shfl_xor(p, 2);
        p += __shfl_xor(p, 4);
        p += __shfl_xor(p, 8);
        zinv[r] = 1.f / (p + 1e-6f);
    }

    __syncthreads();   // all waves done reading KS-as-K before overwrite
#pragma unroll
    for (int tj = 0; tj < 4; ++tj)
#pragma unroll
        for (int r = 0; r < 4; ++r) {
            const int i = w * 16 + quad * 4 + r;
            const int j = tj * 16 + l15;
            KS[i * LDT + j] = f2bf(j <= i ? sacc[tj][r] : 0.f);
        }
    // NO barrier: O-MFMA a1 reads KS rows [w*16, w*16+16) - wave-private.

    // ---- O = causal(S) V + Q KVpref ---------------------------------------
    f32x4 oacc[4] = {};
#pragma unroll
    for (int k0 = 0; k0 < 64; k0 += 32) {
        bf16x8 a1 = *(const bf16x8*)&KS[(w * 16 + l15) * LDT + k0 + quad * 8];
        bf16x8 a2 = *(const bf16x8*)&Qs[(w * 16 + l15) * LDT + k0 + quad * 8];
#pragma unroll
        for (int tj = 0; tj < 4; ++tj) {
            const int rb = tj * 16 + l15;
            bf16x8 b1 = *(const bf16x8*)&VT[rb * LDT + ((k0 + quad * 8) ^ (rb & 56))];
            bf16x8 b2 = *(const bf16x8*)&KVT[rb * LDT + ((k0 + quad * 8) ^ (rb & 56))];
            oacc[tj] = __builtin_amdgcn_mfma_f32_16x16x32_bf16(a1, b1, oacc[tj], 0, 0, 0);
            oacc[tj] = __builtin_amdgcn_mfma_f32_16x16x32_bf16(a2, b2, oacc[tj], 0, 0, 0);
        }
    }
    const size_t arowbase = (size_t)b * 2048 + c * 64;   // attnb stays [b,t][h,e]
#pragma unroll
    for (int tj = 0; tj < 4; ++tj)
#pragma unroll
        for (int r = 0; r < 4; ++r) {
            const int i = w * 16 + quad * 4 + r;
            const int e = tj * 16 + l15;
            attnb[(arowbase + i) * 1024 + h * 64 + e] = f2bf(oacc[tj][r] * zinv[r]);
        }
}

// ---------------- Kernel 5: output projection GEMM, 128x64 tile ------------
__global__ __launch_bounds__(256) void gemm_out(
    const short* __restrict__ attnb, const short* __restrict__ Wob,
    const float* __restrict__ bo, float* __restrict__ outp)
{
    __shared__ short As[128 * 32];
    __shared__ short Bs[64 * 32];
    const int tid = threadIdx.x;
    const int bm = blockIdx.x, bn = blockIdx.y;      // 32 x 16
    const int m0 = bm << 7, n0 = bn << 6;
    const int wave = tid >> 6, lane = tid & 63;
    const int wm = (wave & 1) << 6, wn = (wave >> 1) << 5;
    const int l15 = lane & 15, quad = lane >> 4;

    const int lrow = lane >> 2;
    const int lcol = (((lane & 3) ^ ((lane >> 3) & 3)) << 3);   // swizzle
    const short* gp[3]; short* lp[3];
#pragma unroll
    for (int cc = 0; cc < 3; ++cc) {
        const int ch = wave * 3 + cc;
        if (ch < 8) {
            gp[cc] = attnb + (size_t)(m0 + ch * 16 + lrow) * 1024 + lcol;
            lp[cc] = &As[ch * 512];
        } else {
            gp[cc] = Wob + (size_t)(n0 + (ch - 8) * 16 + lrow) * 1024 + lcol;
            lp[cc] = &Bs[(ch - 8) * 512];
        }
    }
    const int rslot = (quad ^ ((l15 >> 1) & 3)) << 3;           // swizzle

    f32x4 acc[4][2] = {};
    for (int k0 = 0; k0 < 1024; k0 += 32) {
        __syncthreads();
        gl_lds16(gp[0] + k0, lp[0]);
        gl_lds16(gp[1] + k0, lp[1]);
        gl_lds16(gp[2] + k0, lp[2]);
        __syncthreads();
        bf16x8 a[4], b[2];
#pragma unroll
        for (int i = 0; i < 4; ++i) a[i] = *(const bf16x8*)&As[(wm + i * 16 + l15) * 32 + rslot];
#pragma unroll
        for (int j = 0; j < 2; ++j) b[j] = *(const bf16x8*)&Bs[(wn + j * 16 + l15) * 32 + rslot];
#pragma unroll
        for (int i = 0; i < 4; ++i)
#pragma unroll
            for (int j = 0; j < 2; ++j)
                acc[i][j] = __builtin_amdgcn_mfma_f32_16x16x32_bf16(a[i], b[j], acc[i][j], 0, 0, 0);
    }

#pragma unroll
    for (int i = 0; i < 4; ++i)
#pragma unroll
        for (int j = 0; j < 2; ++j) {
            const int col = n0 + wn + j * 16 + l15;
            const float bv_ = bo[col];
#pragma unroll
            for (int r = 0; r < 4; ++r) {
                const int row = m0 + wm + i * 16 + quad * 4 + r;
                outp[(size_t)row * 1024 + col] = acc[i][j][r] + bv_;
            }
        }
}

// ---------------------------------------------------------------------------
extern "C" void kernel_launch(void* const* d_in, const int* in_sizes, int n_in,
                              void* d_out, int out_size, void* d_ws, size_t ws_size,
                              hipStream_t stream)
{
    const float* x  = (const float*)d_in[0];
    const float* Wq = (const float*)d_in[1];
    const float* bq = (const float*)d_in[2];
    const float* Wk = (const float*)d_in[3];
    const float* bk = (const float*)d_in[4];
    const float* Wv = (const float*)d_in[5];
    const float* bv = (const float*)d_in[6];
    const float* Wo = (const float*)d_in[7];
    const float* bo = (const float*)d_in[8];

    char* ws = (char*)d_ws;
    short* xb     = (short*)(ws + 0);          //  8 MB [4096][1024] bf16
    short* Wqb    = (short*)(ws + 8388608);    //  2 MB
    short* Wkb    = (short*)(ws + 10485760);   //  2 MB
    short* Wvb    = (short*)(ws + 12582912);   //  2 MB
    short* Wob    = (short*)(ws + 14680064);   //  2 MB
    short* Qb     = (short*)(ws + 16777216);   //  8 MB [bh*2048+t][64]
    short* Kb     = (short*)(ws + 25165824);   //  8 MB [bh*2048+t][64]
    short* Vb     = (short*)(ws + 33554432);   //  8 MB [bh*2048+t][64]
    short* KVsum  = (short*)(ws + 41943040);   //  8 MB [bh][c][d*64+e] bf16
    short* KVpref = (short*)(ws + 50331648);   //  8 MB bf16, same layout
    short* attnb  = (short*)(ws + 58720256);   //  8 MB [b,t][h*64+e]
    float* ksum   = (float*)(ws + 67108864);   // 256 KB
    float* kpref  = (float*)(ws + 67371008);   // 256 KB
    float* outp   = (float*)d_out;

    convert_bf16<<<4096, 256, 0, stream>>>(x, Wq, Wk, Wv, Wo, xb, Wqb, Wkb, Wvb, Wob);
    gemm_qkv   <<<dim3(32, 24), 256, 0, stream>>>(xb, Wqb, Wkb, Wvb, bq, bk, bv, Qb, Kb, Vb);
    chunk_sums <<<dim3(32, 32), 256, 0, stream>>>(Kb, Vb, KVsum, ksum);
    scan_chunks<<<dim3(16, 32), 256, 0, stream>>>(KVsum, ksum, KVpref, kpref);
    attn_chunk <<<dim3(32, 32), 256, 0, stream>>>(Qb, Kb, Vb, KVpref, kpref, attnb);
    gemm_out   <<<dim3(32, 16), 256, 0, stream>>>(attnb, Wob, bo, outp);
}